// Round 15
// baseline (4048.534 us; speedup 1.0000x reference)
//
#include <hip/hip_runtime.h>
#include <hip/hip_bf16.h>

// ---------------------------------------------------------------------------
// CTM round 14: tick loop 8 -> 7 launches. qh GEMV fused into final_kernel
// using the COALESCED pattern proven for the out-head (8 lanes/row, contiguous
// short8 chunks, shfl-xor reduce, padded-LDS syncA) -- fixing round-10's
// uncoalesced-fusion regression. Attention reads qhb directly; syncA global
// round-trip removed; qh0_kernel seeds tick 0. kh|vh merged GEMM kept (r13).
// ---------------------------------------------------------------------------

#define B_ 64
#define S_ 512
#define F_ 1024
#define DMODEL 2048
#define DMEM 32
#define DIN 1024
#define NH 16
#define DH 64
#define DOUT 1000
#define NSYNC 512
#define TICKS 16
#define HNLM 32
#define HIST_W 48

typedef __attribute__((ext_vector_type(8))) short short8;
typedef __attribute__((ext_vector_type(4))) float f32x4;

__device__ inline void store_f(float* p, float v) { *p = v; }
__device__ inline void store_f(__hip_bfloat16* p, float v) { *p = __float2bfloat16(v); }

__device__ inline short f2bs(float f) {
  __hip_bfloat16 h = __float2bfloat16(f);
  return *reinterpret_cast<short*>(&h);
}

__device__ inline float bfs(short x) {
  return __uint_as_float(((unsigned)(unsigned short)x) << 16);
}

__device__ inline float gelu_f(float x) {
  float x3 = x * x * x;
  return 0.5f * x * (1.f + tanhf(0.7978845608028654f * (x + 0.044715f * x3)));
}

__device__ inline float bf_lo(unsigned v) { return __uint_as_float(v << 16); }
__device__ inline float bf_hi(unsigned v) { return __uint_as_float(v & 0xffff0000u); }

// ---------------- weight prep ----------------
// W (K,N) fp32 -> Wt rows n: Wt[n*ldw + koff + k] = W[k*N + n], zero-pad n>=N
__global__ __launch_bounds__(256) void transpose_bf16_kernel(const float* __restrict__ W,
                                                             __hip_bfloat16* __restrict__ Wt,
                                                             int K, int N, int Npad, int ldw,
                                                             int koff) {
  __shared__ float t[32][33];
  const int tx = threadIdx.x, ty = threadIdx.y;  // 32 x 8
  const int n0 = blockIdx.x * 32, k0 = blockIdx.y * 32;
#pragma unroll
  for (int i = 0; i < 4; i++) {
    int k = k0 + ty + i * 8;
    t[ty + i * 8][tx] = (k < K && n0 + tx < N) ? W[(size_t)k * N + n0 + tx] : 0.f;
  }
  __syncthreads();
#pragma unroll
  for (int i = 0; i < 4; i++) {
    int n = n0 + ty + i * 8;
    if (n < Npad && k0 + tx < K)
      Wt[(size_t)n * ldw + koff + k0 + tx] = __float2bfloat16(t[tx][ty + i * 8]);
  }
}

__global__ void conv_bf16_kernel(const float* __restrict__ src, __hip_bfloat16* __restrict__ dst,
                                 int n) {
  int i = blockIdx.x * 256 + threadIdx.x;
  if (i < n) dst[i] = __float2bfloat16(src[i]);
}

__global__ void bqaq_kernel(const float* __restrict__ b_q, const float* __restrict__ b_aq,
                            const __hip_bfloat16* __restrict__ Wt_aq, float* __restrict__ b_qaq) {
  int n = blockIdx.x * 256 + threadIdx.x;
  if (n >= DIN) return;
  const __hip_bfloat16* wr = Wt_aq + (size_t)n * DIN;
  float s = b_aq[n];
  for (int k = 0; k < DIN; k++) s += b_q[k] * __bfloat162float(wr[k]);
  b_qaq[n] = s;
}

// b_s1c[n] = b_s1[n] + sum_{k<1024} b_ao[k] * W_s1[k, n]   (n < 2048)
__global__ void bs1c_kernel(const float* __restrict__ b_s1, const float* __restrict__ b_ao,
                            const float* __restrict__ W_s1, float* __restrict__ b_s1c) {
  int n = blockIdx.x * 256 + threadIdx.x;
  if (n >= DMODEL) return;
  float s = b_s1[n];
  for (int k = 0; k < DIN; k++) s += b_ao[k] * W_s1[(size_t)k * DMODEL + n];
  b_s1c[n] = s;
}

// ---------------- big MFMA GEMM (precompute), XCD-chunked swizzle ----------
// TRANSC: 0 = row-major C[M,N]; 1 = C^T with row-stride M; 2 = attn layout;
//         3 = combined kh|vh attn layout (N=2048; col>=1024 -> vh region)
__device__ inline short8 load_chunk(const __hip_bfloat16* p) {
  return *reinterpret_cast<const short8*>(p);
}
__device__ inline short8 load_chunk(const float* p) {
  short8 r;
#pragma unroll
  for (int j = 0; j < 8; j++) r[j] = f2bs(p[j]);
  return r;
}

template <int TRANSC, typename TA, typename TC>
__global__ __launch_bounds__(256) void gemm_big(const TA* __restrict__ A,
                                                const __hip_bfloat16* __restrict__ Bt,
                                                const float* __restrict__ bias,
                                                TC* __restrict__ C, int M, int N, int K) {
  __shared__ short lsA[128 * 64];
  __shared__ short lsB[128 * 64];
  const int tid = threadIdx.x;
  const int l = tid & 63, w = tid >> 6;
  const int wr = (w >> 1) * 64, wc = (w & 1) * 64;
  const int nwg = gridDim.x * gridDim.y;
  const int flat = blockIdx.y * gridDim.x + blockIdx.x;
  const int wk = (flat & 7) * (nwg >> 3) + (flat >> 3);  // nwg % 8 == 0
  const int brow = (wk / gridDim.x) * 128, bcol = (wk % gridDim.x) * 128;
  f32x4 acc[4][4];
#pragma unroll
  for (int i = 0; i < 4; i++)
#pragma unroll
    for (int j = 0; j < 4; j++)
#pragma unroll
      for (int r = 0; r < 4; r++) acc[i][j][r] = 0.f;

  short8 ra[4], rb[4];
  auto gload = [&](int k0) {
#pragma unroll
    for (int q = 0; q < 4; q++) {
      int i = tid + q * 256;
      int row = i >> 3, c = i & 7;
      ra[q] = load_chunk(A + (size_t)(brow + row) * K + k0 + c * 8);
      rb[q] = load_chunk(Bt + (size_t)(bcol + row) * K + k0 + c * 8);
    }
  };
  auto lwrite = [&]() {
#pragma unroll
    for (int q = 0; q < 4; q++) {
      int i = tid + q * 256;
      int row = i >> 3, c = i & 7;
      int sw = c ^ (row & 7);
      *reinterpret_cast<short8*>(&lsA[row * 64 + sw * 8]) = ra[q];
      *reinterpret_cast<short8*>(&lsB[row * 64 + sw * 8]) = rb[q];
    }
  };
  gload(0);
  for (int k0 = 0; k0 < K; k0 += 64) {
    __syncthreads();
    lwrite();
    if (k0 + 64 < K) gload(k0 + 64);
    __syncthreads();
#pragma unroll
    for (int ks = 0; ks < 2; ks++) {
      short8 af[4], bfv[4];
#pragma unroll
      for (int mi = 0; mi < 4; mi++) {
        int row = wr + mi * 16 + (l & 15);
        int c = ks * 4 + (l >> 4);
        af[mi] = *reinterpret_cast<const short8*>(&lsA[row * 64 + (c ^ (row & 7)) * 8]);
      }
#pragma unroll
      for (int ni = 0; ni < 4; ni++) {
        int row = wc + ni * 16 + (l & 15);
        int c = ks * 4 + (l >> 4);
        bfv[ni] = *reinterpret_cast<const short8*>(&lsB[row * 64 + (c ^ (row & 7)) * 8]);
      }
#pragma unroll
      for (int mi = 0; mi < 4; mi++)
#pragma unroll
        for (int ni = 0; ni < 4; ni++)
          acc[mi][ni] =
              __builtin_amdgcn_mfma_f32_16x16x32_bf16(af[mi], bfv[ni], acc[mi][ni], 0, 0, 0);
    }
  }
#pragma unroll
  for (int mi = 0; mi < 4; mi++)
#pragma unroll
    for (int ni = 0; ni < 4; ni++)
#pragma unroll
      for (int r = 0; r < 4; r++) {
        int row = brow + wr + mi * 16 + (l >> 4) * 4 + r;
        int col = bcol + wc + ni * 16 + (l & 15);
        float v = acc[mi][ni][r];
        if (bias) v += bias[col];
        if (TRANSC == 1) {
          store_f(&C[(size_t)col * M + row], v);
        } else if (TRANSC == 2) {
          int bb = row >> 9, s = row & 511, hh = col >> 6, dd = col & 63;
          store_f(&C[(((size_t)(bb * 16 + hh) * 512) + s) * 64 + dd], v);
        } else if (TRANSC == 3) {
          int bb = row >> 9, s = row & 511, hh2 = col >> 6, dd = col & 63;
          size_t base = (hh2 >= 16) ? (size_t)B_ * S_ * DIN : 0;  // vh after kh
          store_f(&C[base + (((size_t)(bb * 16 + (hh2 & 15)) * 512) + s) * 64 + dd], v);
        } else {
          store_f(&C[(size_t)row * N + col], v);
        }
      }
}

// ---------------- LayerNorm (strided/typed output) ----------------
template <typename TOUT>
__global__ __launch_bounds__(256) void ln_kernel(const float* __restrict__ x,
                                                 const float* __restrict__ g,
                                                 const float* __restrict__ be,
                                                 TOUT* __restrict__ out, int C,
                                                 size_t row_stride, int col_stride) {
  const int row = blockIdx.x;
  const int tid = threadIdx.x;
  const float* xr = x + (size_t)row * C;
  float s = 0.f, s2 = 0.f;
  for (int c = tid; c < C; c += 256) {
    float v = xr[c];
    s += v;
    s2 += v * v;
  }
  __shared__ float r1[256], r2[256];
  r1[tid] = s;
  r2[tid] = s2;
  __syncthreads();
  for (int st = 128; st > 0; st >>= 1) {
    if (tid < st) {
      r1[tid] += r1[tid + st];
      r2[tid] += r2[tid + st];
    }
    __syncthreads();
  }
  float mean = r1[0] / C;
  float var = r2[0] / C - mean * mean;
  float inv = 1.0f / sqrtf(var + 1e-5f);
  for (int c = tid; c < C; c += 256) {
    float v = (xr[c] - mean) * inv * g[c] + be[c];
    store_f(&out[(size_t)row * row_stride + (size_t)c * col_stride], v);
  }
}

// ---------------- init kernels ----------------
__global__ void init_pre_kernel(const float* __restrict__ init_state,
                                __hip_bfloat16* __restrict__ pre) {
  int i = blockIdx.x * 256 + threadIdx.x;
  if (i >= B_ * DMODEL) return;
  int b = i >> 11, j = i & (DMODEL - 1);
  pre[(size_t)b * 3072 + DIN + j] = __float2bfloat16(init_state[j]);
}

__global__ void init_hist_kernel(const float* __restrict__ init_hist, float* __restrict__ hist) {
  int i = blockIdx.x * 256 + threadIdx.x;
  if (i >= B_ * DMODEL * DMEM) return;
  int m = i & (DMEM - 1);
  int bd = i >> 5;
  int d = bd & (DMODEL - 1);
  hist[(size_t)bd * HIST_W + m] = init_hist[d * DMEM + m];
}

__global__ void init_sync_kernel(const float* __restrict__ init_state,
                                 const float* __restrict__ decay_action,
                                 const float* __restrict__ decay_out,
                                 const int* __restrict__ la, const int* __restrict__ ra,
                                 const int* __restrict__ lo, const int* __restrict__ ro,
                                 float* __restrict__ aA, float* __restrict__ bA,
                                 float* __restrict__ aO, float* __restrict__ bO,
                                 float* __restrict__ syncA0, float* __restrict__ rAv,
                                 float* __restrict__ rOv) {
  int i = blockIdx.x * 256 + threadIdx.x;
  if (i >= B_ * NSYNC) return;
  int j = i & (NSYNC - 1);
  if (i < NSYNC) {
    rAv[i] = expf(-fminf(fmaxf(decay_action[i], 0.f), 15.f));
    rOv[i] = expf(-fminf(fmaxf(decay_out[i], 0.f), 15.f));
  }
  float pA = init_state[la[j]] * init_state[ra[j]];
  aA[i] = pA;
  bA[i] = 1.f;
  syncA0[i] = pA;  // pA / sqrt(1)
  aO[i] = init_state[lo[j]] * init_state[ro[j]];
  bO[i] = 1.f;
}

// qh for tick 0 (coalesced GEMV, same pattern as out-head)
__global__ __launch_bounds__(256) void qh0_kernel(const float* __restrict__ syncA0,
                                                  const __hip_bfloat16* __restrict__ Wt_qaq,
                                                  const float* __restrict__ b_qaq,
                                                  float* __restrict__ qhb) {
  __shared__ float sa_p[520];
  const int b = blockIdx.x;
  const int tid = threadIdx.x;
  for (int j = tid; j < NSYNC; j += 256) sa_p[j + (j >> 6)] = syncA0[(size_t)b * NSYNC + j];
  __syncthreads();
  const int lk = tid & 7;
  const int rg = tid >> 3;
  for (int it = 0; it < 32; ++it) {
    int n = it * 32 + rg;
    const short8* wr8 = reinterpret_cast<const short8*>(Wt_qaq + (size_t)n * NSYNC);
    float sacc = 0.f;
#pragma unroll
    for (int q = 0; q < 8; ++q) {
      short8 w8 = wr8[q * 8 + lk];
#pragma unroll
      for (int j = 0; j < 8; ++j) sacc += sa_p[q * 65 + lk * 8 + j] * bfs(w8[j]);
    }
    sacc += __shfl_xor(sacc, 1);
    sacc += __shfl_xor(sacc, 2);
    sacc += __shfl_xor(sacc, 4);
    if (lk == 0) qhb[(size_t)b * DIN + n] = sacc + b_qaq[n];
  }
}

// ---------------- 64xN-tile MFMA matmul body (tick GEMMs) ----------------
template <typename EPI>
__device__ __forceinline__ void mm_tile64(const __hip_bfloat16* __restrict__ A, int lda,
                                          const __hip_bfloat16* __restrict__ Bt, int ldb,
                                          int bcol, int kb, int kchunk, int tid, short* lsA,
                                          short* lsB, EPI epi) {
  const int l = tid & 63, w = tid >> 6;
  f32x4 acc[4];
#pragma unroll
  for (int i = 0; i < 4; i++)
#pragma unroll
    for (int r = 0; r < 4; r++) acc[i][r] = 0.f;
  short8 ra[2], rb[2];
  auto gload = [&](int k0) {
#pragma unroll
    for (int q = 0; q < 2; q++) {
      int i = tid + q * 256;
      int row = i >> 3, c = i & 7;
      ra[q] = *reinterpret_cast<const short8*>(A + (size_t)row * lda + k0 + c * 8);
      rb[q] = *reinterpret_cast<const short8*>(Bt + (size_t)(bcol + row) * ldb + k0 + c * 8);
    }
  };
  auto lwrite = [&]() {
#pragma unroll
    for (int q = 0; q < 2; q++) {
      int i = tid + q * 256;
      int row = i >> 3, c = i & 7;
      int sw = c ^ (row & 7);
      *reinterpret_cast<short8*>(&lsA[row * 64 + sw * 8]) = ra[q];
      *reinterpret_cast<short8*>(&lsB[row * 64 + sw * 8]) = rb[q];
    }
  };
  gload(kb);
  for (int k0 = kb; k0 < kb + kchunk; k0 += 64) {
    __syncthreads();
    lwrite();
    if (k0 + 64 < kb + kchunk) gload(k0 + 64);
    __syncthreads();
#pragma unroll
    for (int ks = 0; ks < 2; ks++) {
      int rowa = w * 16 + (l & 15);
      int c = ks * 4 + (l >> 4);
      short8 af = *reinterpret_cast<const short8*>(&lsA[rowa * 64 + (c ^ (rowa & 7)) * 8]);
#pragma unroll
      for (int ni = 0; ni < 4; ni++) {
        int rowb = ni * 16 + (l & 15);
        short8 bfv = *reinterpret_cast<const short8*>(&lsB[rowb * 64 + (c ^ (rowb & 7)) * 8]);
        acc[ni] = __builtin_amdgcn_mfma_f32_16x16x32_bf16(af, bfv, acc[ni], 0, 0, 0);
      }
    }
  }
#pragma unroll
  for (int ni = 0; ni < 4; ni++)
#pragma unroll
    for (int r = 0; r < 4; r++) {
      int m = w * 16 + (l >> 4) * 4 + r;
      int n = bcol + ni * 16 + (l & 15);
      epi(m, n, acc[ni][r]);
    }
}

// ---------------- split-K partial GEMM (atomic-free) ----------------
__global__ __launch_bounds__(256) void gemm_part(const __hip_bfloat16* __restrict__ A, int lda,
                                                 const __hip_bfloat16* __restrict__ Bt, int ldb,
                                                 float* __restrict__ part, int N, int kchunk) {
  __shared__ short lsA[64 * 64];
  __shared__ short lsB[64 * 64];
  const int tid = threadIdx.x;
  const int nt = blockIdx.x, ks = blockIdx.y;
  mm_tile64(A, lda, Bt, ldb, nt * 64, ks * kchunk, kchunk, tid, lsA, lsB,
            [&](int m, int n, float v) { part[((size_t)(ks * 64 + m)) * N + n] = v; });
}

// reduce(KS) + bias + gelu -> h1 (bf16)
__global__ void s1_red_kernel(const float* __restrict__ part, const float* __restrict__ bias,
                              __hip_bfloat16* __restrict__ h1, int KS) {
  int i = blockIdx.x * 256 + threadIdx.x;  // 64*2048
  int m = i >> 11, n = i & 2047;
  float s = bias[n];
  for (int k = 0; k < KS; k++) s += part[((size_t)(k * 64 + m)) * DMODEL + n];
  h1[(size_t)m * DMODEL + n] = __float2bfloat16(gelu_f(s));
}

// reduce(KS) + bias + LayerNorm -> hist slot 32+t (one block per batch row)
__global__ __launch_bounds__(256) void s2_red_ln_kernel(const float* __restrict__ part,
                                                        const float* __restrict__ bias,
                                                        const float* __restrict__ g,
                                                        const float* __restrict__ be,
                                                        float* __restrict__ hist, int KS, int t) {
  __shared__ float r1[256], r2[256];
  const int b = blockIdx.x;
  const int tid = threadIdx.x;
  float v8[8];
  float s = 0.f, s2 = 0.f;
#pragma unroll
  for (int i = 0; i < 8; i++) {
    int n = tid + i * 256;
    float x = bias[n];
    for (int k = 0; k < KS; k++) x += part[((size_t)(k * 64 + b)) * DMODEL + n];
    v8[i] = x;
    s += x;
    s2 += x * x;
  }
  r1[tid] = s;
  r2[tid] = s2;
  __syncthreads();
  for (int st = 128; st > 0; st >>= 1) {
    if (tid < st) {
      r1[tid] += r1[tid + st];
      r2[tid] += r2[tid + st];
    }
    __syncthreads();
  }
  float mean = r1[0] / DMODEL;
  float var = r2[0] / DMODEL - mean * mean;
  float inv = 1.f / sqrtf(var + 1e-5f);
#pragma unroll
  for (int i = 0; i < 8; i++) {
    int n = tid + i * 256;
    float pa = (v8[i] - mean) * inv * g[n] + be[n];
    hist[((size_t)b * DMODEL + n) * HIST_W + 32 + t] = pa;
  }
}

// ---------------- attention (head-major K/V) -> pre[:, :1024] ----------------
__global__ __launch_bounds__(256) void attn_kernel(const float* __restrict__ qhb,
                                                   const __hip_bfloat16* __restrict__ kh,
                                                   const __hip_bfloat16* __restrict__ vh,
                                                   __hip_bfloat16* __restrict__ pre) {
  __shared__ float qs[64];
  __shared__ float wv[512];
  __shared__ float red[256];
  __shared__ float red2[2048];
  const int u = blockIdx.x;
  const int b = u >> 4, h = u & (NH - 1);
  const int tid = threadIdx.x;
  const __hip_bfloat16* Kp = kh + (size_t)u * (S_ * DH);
  const __hip_bfloat16* Vp = vh + (size_t)u * (S_ * DH);
  if (tid < DH) qs[tid] = qhb[(size_t)b * DIN + h * DH + tid];
  __syncthreads();
  float sc[2];
#pragma unroll
  for (int r = 0; r < 2; ++r) {
    int s = tid + r * 256;
    const short8* kp = reinterpret_cast<const short8*>(Kp + (size_t)s * DH);
    float accv = 0.f;
#pragma unroll
    for (int q = 0; q < 8; ++q) {
      short8 kk = kp[q];
#pragma unroll
      for (int j = 0; j < 8; ++j) accv += qs[q * 8 + j] * bfs(kk[j]);
    }
    sc[r] = accv * 0.125f;
  }
  red[tid] = fmaxf(sc[0], sc[1]);
  __syncthreads();
  for (int st = 128; st > 0; st >>= 1) {
    if (tid < st) red[tid] = fmaxf(red[tid], red[tid + st]);
    __syncthreads();
  }
  const float mx = red[0];
  __syncthreads();
  float e0 = expf(sc[0] - mx), e1 = expf(sc[1] - mx);
  wv[tid] = e0;
  wv[tid + 256] = e1;
  red[tid] = e0 + e1;
  __syncthreads();
  for (int st = 128; st > 0; st >>= 1) {
    if (tid < st) red[tid] += red[tid + st];
    __syncthreads();
  }
  const float invZ = 1.f / red[0];
  __syncthreads();
  const int d8 = tid & 7, sg = tid >> 3;
  float pacc[8];
#pragma unroll
  for (int j = 0; j < 8; ++j) pacc[j] = 0.f;
  for (int s = sg; s < S_; s += 32) {
    float wgt = wv[s];
    short8 vvv = *reinterpret_cast<const short8*>(Vp + (size_t)s * DH + d8 * 8);
#pragma unroll
    for (int j = 0; j < 8; ++j) pacc[j] += wgt * bfs(vvv[j]);
  }
#pragma unroll
  for (int j = 0; j < 8; ++j) red2[sg * 64 + d8 * 8 + j] = pacc[j];
  __syncthreads();
  if (tid < DH) {
    float r = 0.f;
#pragma unroll
    for (int g2 = 0; g2 < 32; ++g2) r += red2[g2 * 64 + tid];
    pre[(size_t)b * 3072 + h * DH + tid] = __float2bfloat16(r * invZ);
  }
}

// ---------------- per-neuron NLM ----------------
__global__ __launch_bounds__(256) void nlm_kernel(const float* __restrict__ hist,
                                                  const float* __restrict__ W1,
                                                  const float* __restrict__ b1,
                                                  const float* __restrict__ W2,
                                                  const float* __restrict__ b2,
                                                  float* __restrict__ out, int t) {
  __shared__ float w1s[4096];
  __shared__ float b1s[128];
  const int tid = threadIdx.x;
  const int d0 = blockIdx.x * 4;
  for (int i = tid; i < 4096; i += 256) w1s[i] = W1[(size_t)d0 * 1024 + i];
  if (tid < 128) b1s[tid] = b1[d0 * 32 + tid];
  __syncthreads();
  const int b = tid & 63, dsub = tid >> 6;
  const int d = d0 + dsub;
  const float* hw = hist + ((size_t)(b * DMODEL + d)) * HIST_W + (t + 1);
  float win[DMEM];
#pragma unroll
  for (int m = 0; m < DMEM; ++m) win[m] = hw[m];
  const float* w1 = w1s + dsub * 1024;
  const float* bb = b1s + dsub * 32;
  const float* w2 = W2 + d * HNLM;
  float acc = 0.f;
  for (int h = 0; h < HNLM; ++h) {
    float s = bb[h];
#pragma unroll
    for (int m = 0; m < DMEM; ++m) s += win[m] * w1[m * HNLM + h];
    acc += fmaxf(s, 0.f) * w2[h];
  }
  out[(size_t)b * DMODEL + d] = acc + b2[d];
}

// ---------------- final fused kernel: LN -> sync updates -> pre pack ->
//   coalesced qh GEMV (next tick) + coalesced out-head GEMV + entropy.
__global__ __launch_bounds__(256) void final_kernel(
    const float* __restrict__ nlmraw, const float* __restrict__ g_n,
    const float* __restrict__ be_n, const int* __restrict__ la, const int* __restrict__ ra,
    const int* __restrict__ lo, const int* __restrict__ ro, const float* __restrict__ rAv,
    const float* __restrict__ rOv, float* __restrict__ aA, float* __restrict__ bA,
    float* __restrict__ aO, float* __restrict__ bO, __hip_bfloat16* __restrict__ pre,
    const __hip_bfloat16* __restrict__ Wt_qaq, const float* __restrict__ b_qaq,
    float* __restrict__ qhb, const __hip_bfloat16* __restrict__ Wt_out,
    const float* __restrict__ b_out, float* __restrict__ outp, int t) {
  __shared__ float arow[2048];
  __shared__ float sa_p[520];  // syncA (t+1), padded
  __shared__ float so_p[520];  // syncO (t), padded
  __shared__ float pv[1024];
  __shared__ float red[256], red2[256];
  const int b = blockIdx.x;
  const int tid = threadIdx.x;
  const float* xr = nlmraw + (size_t)b * DMODEL;
  float xv[8];
  float s = 0.f, s2 = 0.f;
#pragma unroll
  for (int i = 0; i < 8; i++) {
    float x = xr[tid + i * 256];
    xv[i] = x;
    s += x;
    s2 += x * x;
  }
  red[tid] = s;
  red2[tid] = s2;
  __syncthreads();
  for (int st = 128; st > 0; st >>= 1) {
    if (tid < st) {
      red[tid] += red[tid + st];
      red2[tid] += red2[tid + st];
    }
    __syncthreads();
  }
  float mean = red[0] / DMODEL;
  float var = red2[0] / DMODEL - mean * mean;
  float inv = 1.f / sqrtf(var + 1e-5f);
  __syncthreads();
#pragma unroll
  for (int i = 0; i < 8; i++) {
    int n = tid + i * 256;
    float av = (xv[i] - mean) * inv * g_n[n] + be_n[n];
    arow[n] = av;
    pre[(size_t)b * 3072 + DIN + n] = __float2bfloat16(av);  // act for tick t+1
  }
  __syncthreads();
  for (int j = tid; j < NSYNC; j += 256) {
    size_t idx = (size_t)b * NSYNC + j;
    float pA = arow[la[j]] * arow[ra[j]];
    float r = rAv[j];
    float av2 = r * aA[idx] + pA, bv2 = r * bA[idx] + 1.f;
    aA[idx] = av2;
    bA[idx] = bv2;
    sa_p[j + (j >> 6)] = av2 / sqrtf(bv2);  // syncA (t+1) in padded LDS
    float pO = arow[lo[j]] * arow[ro[j]];
    float ro2 = rOv[j];
    float av3 = ro2 * aO[idx] + pO, bv3 = ro2 * bO[idx] + 1.f;
    aO[idx] = av3;
    bO[idx] = bv3;
    so_p[j + (j >> 6)] = av3 / sqrtf(bv3);  // syncO (t) in padded LDS
  }
  __syncthreads();
  const int lk = tid & 7;   // k-slice within row
  const int rg = tid >> 3;  // row-group 0..31
  // qh GEMV for next tick (coalesced): qhb[b,n] = sa . Wt_qaq[n,:] + b_qaq[n]
  for (int it = 0; it < 32; ++it) {
    int n = it * 32 + rg;
    const short8* wr8 = reinterpret_cast<const short8*>(Wt_qaq + (size_t)n * NSYNC);
    float sacc = 0.f;
#pragma unroll
    for (int q = 0; q < 8; ++q) {
      short8 w8 = wr8[q * 8 + lk];
#pragma unroll
      for (int j = 0; j < 8; ++j) sacc += sa_p[q * 65 + lk * 8 + j] * bfs(w8[j]);
    }
    sacc += __shfl_xor(sacc, 1);
    sacc += __shfl_xor(sacc, 2);
    sacc += __shfl_xor(sacc, 4);
    if (lk == 0) qhb[(size_t)b * DIN + n] = sacc + b_qaq[n];
  }
  // out head (coalesced): pred = so . W_out^T + b_out
  for (int it = 0; it < 32; ++it) {
    int n = it * 32 + rg;
    float sacc = 0.f;
    if (n < DOUT) {
      const short8* wr8 = reinterpret_cast<const short8*>(Wt_out + (size_t)n * NSYNC);
#pragma unroll
      for (int q = 0; q < 8; ++q) {
        short8 w8 = wr8[q * 8 + lk];
#pragma unroll
        for (int j = 0; j < 8; ++j) sacc += so_p[q * 65 + lk * 8 + j] * bfs(w8[j]);
      }
    }
    sacc += __shfl_xor(sacc, 1);
    sacc += __shfl_xor(sacc, 2);
    sacc += __shfl_xor(sacc, 4);
    if (lk == 0 && n < DOUT) pv[n] = sacc + b_out[n];
  }
  __syncthreads();
  float m = -1e30f;
  for (int o = tid; o < DOUT; o += 256) m = fmaxf(m, pv[o]);
  red[tid] = m;
  __syncthreads();
  for (int st = 128; st > 0; st >>= 1) {
    if (tid < st) red[tid] = fmaxf(red[tid], red[tid + st]);
    __syncthreads();
  }
  m = red[0];
  __syncthreads();
  float z = 0.f, s1 = 0.f;
  for (int o = tid; o < DOUT; o += 256) {
    float wv2 = pv[o] - m;
    float e = expf(wv2);
    z += e;
    s1 += e * wv2;
  }
  red[tid] = z;
  __syncthreads();
  for (int st = 128; st > 0; st >>= 1) {
    if (tid < st) red[tid] += red[tid + st];
    __syncthreads();
  }
  const float Z = red[0];
  __syncthreads();
  red[tid] = s1;
  __syncthreads();
  for (int st = 128; st > 0; st >>= 1) {
    if (tid < st) red[tid] += red[tid + st];
    __syncthreads();
  }
  const float S1 = red[0];
  const float ne = -(S1 / Z - logf(Z)) / 6.907755278982137f;
  for (int o = tid; o < DOUT; o += 256) outp[((size_t)b * DOUT + o) * TICKS + t] = pv[o];
  if (tid == 0) {
    float* c = outp + (size_t)B_ * DOUT * TICKS;
    c[b * 2 * TICKS + t] = ne;
    c[b * 2 * TICKS + TICKS + t] = 1.f - ne;
  }
}

// ---------------------------------------------------------------------------
extern "C" void kernel_launch(void* const* d_in, const int* in_sizes, int n_in,
                              void* d_out, int out_size, void* d_ws, size_t ws_size,
                              hipStream_t stream) {
  const float* x = (const float*)d_in[0];
  const float* W_kv = (const float*)d_in[1];
  const float* b_kv = (const float*)d_in[2];
  const float* g_kv = (const float*)d_in[3];
  const float* be_kv = (const float*)d_in[4];
  const float* W_q = (const float*)d_in[5];
  const float* b_q = (const float*)d_in[6];
  const float* W_aq = (const float*)d_in[7];
  const float* b_aq = (const float*)d_in[8];
  const float* W_ak = (const float*)d_in[9];
  const float* b_ak = (const float*)d_in[10];
  const float* W_av = (const float*)d_in[11];
  const float* b_av = (const float*)d_in[12];
  const float* W_ao = (const float*)d_in[13];
  const float* b_ao = (const float*)d_in[14];
  const float* W_s1 = (const float*)d_in[15];
  const float* b_s1 = (const float*)d_in[16];
  const float* W_s2 = (const float*)d_in[17];
  const float* b_s2 = (const float*)d_in[18];
  const float* g_s = (const float*)d_in[19];
  const float* be_s = (const float*)d_in[20];
  const float* W_n1 = (const float*)d_in[21];
  const float* b_n1 = (const float*)d_in[22];
  const float* W_n2 = (const float*)d_in[23];
  const float* b_n2 = (const float*)d_in[24];
  const float* g_n = (const float*)d_in[25];
  const float* be_n = (const float*)d_in[26];
  const float* init_state = (const float*)d_in[27];
  const float* init_hist = (const float*)d_in[28];
  const float* decay_action = (const float*)d_in[29];
  const float* decay_out = (const float*)d_in[30];
  const float* W_out = (const float*)d_in[31];
  const float* b_out = (const float*)d_in[32];
  const int* idx_la = (const int*)d_in[33];
  const int* idx_ra = (const int*)d_in[34];
  const int* idx_lo = (const int*)d_in[35];
  const int* idx_ro = (const int*)d_in[36];
  float* out = (float*)d_out;

  // ---- workspace carve ----
  char* wsb = (char*)d_ws;
  size_t off = 0;
  auto alloc = [&](size_t bytes) -> char* {
    char* p = wsb + off;
    off += (bytes + 255) & ~(size_t)255;
    return p;
  };
  const size_t MS = (size_t)B_ * S_;  // 32768
  char* regionA = alloc(MS * DIN * 4);  // kvraw fp32; later kh+vh bf16 (head-major)
  __hip_bfloat16* kv = (__hip_bfloat16*)alloc(MS * DIN * 2);
  float* histf = (float*)alloc((size_t)B_ * DMODEL * HIST_W * 4);
  __hip_bfloat16* Wt_kv = (__hip_bfloat16*)alloc((size_t)DIN * F_ * 2);
  __hip_bfloat16* Wt_akav = (__hip_bfloat16*)alloc((size_t)2 * DIN * DIN * 2);  // concat ak|av
  __hip_bfloat16* Wt_aq = (__hip_bfloat16*)alloc((size_t)DIN * DIN * 2);
  __hip_bfloat16* W_ao_b = (__hip_bfloat16*)alloc((size_t)DIN * DIN * 2);
  __hip_bfloat16* W_qb = (__hip_bfloat16*)alloc((size_t)NSYNC * DIN * 2);
  __hip_bfloat16* Wt_qaq = (__hip_bfloat16*)alloc((size_t)DIN * NSYNC * 2);
  __hip_bfloat16* Wts1top = (__hip_bfloat16*)alloc((size_t)DMODEL * DIN * 2);
  __hip_bfloat16* Wt_s1c = (__hip_bfloat16*)alloc((size_t)DMODEL * (DIN + DMODEL) * 2);
  __hip_bfloat16* Wt_s2 = (__hip_bfloat16*)alloc((size_t)DMODEL * DMODEL * 2);
  __hip_bfloat16* Wt_out = (__hip_bfloat16*)alloc((size_t)DOUT * NSYNC * 2);
  float* b_qaq = (float*)alloc(DIN * 4);
  float* b_s1c = (float*)alloc(DMODEL * 4);
  float* b_akav = (float*)alloc((size_t)2 * DIN * 4);
  float* partial = (float*)alloc((size_t)8 * 64 * DMODEL * 4);
  float* aA = (float*)alloc((size_t)B_ * NSYNC * 4);
  float* bA = (float*)alloc((size_t)B_ * NSYNC * 4);
  float* aO = (float*)alloc((size_t)B_ * NSYNC * 4);
  float* bO = (float*)alloc((size_t)B_ * NSYNC * 4);
  float* syncA0 = (float*)alloc((size_t)B_ * NSYNC * 4);
  float* qhb = (float*)alloc((size_t)B_ * DIN * 4);
  __hip_bfloat16* pre = (__hip_bfloat16*)alloc((size_t)B_ * (DIN + DMODEL) * 2);
  __hip_bfloat16* h1 = (__hip_bfloat16*)alloc((size_t)B_ * DMODEL * 2);
  float* nlmraw = (float*)alloc((size_t)B_ * DMODEL * 4);
  float* rAv = (float*)alloc(NSYNC * 4);
  float* rOv = (float*)alloc(NSYNC * 4);

  float* kvraw = (float*)regionA;
  __hip_bfloat16* kh = (__hip_bfloat16*)regionA;                   // [b][h][s][d]
  __hip_bfloat16* vh = (__hip_bfloat16*)(regionA + MS * DIN * 2);  // [b][h][s][d]
  __hip_bfloat16* Wt_ak = Wt_akav;                                 // rows [0,1024)
  __hip_bfloat16* Wt_av = Wt_akav + (size_t)DIN * DIN;             // rows [1024,2048)

  dim3 t32x8(32, 8);
  // ---- weight prep ----
  transpose_bf16_kernel<<<dim3(F_ / 32, DIN / 32), t32x8, 0, stream>>>(W_kv, Wt_kv, F_, DIN, DIN,
                                                                       F_, 0);
  transpose_bf16_kernel<<<dim3(DIN / 32, DIN / 32), t32x8, 0, stream>>>(W_ak, Wt_ak, DIN, DIN,
                                                                        DIN, DIN, 0);
  transpose_bf16_kernel<<<dim3(DIN / 32, DIN / 32), t32x8, 0, stream>>>(W_av, Wt_av, DIN, DIN,
                                                                        DIN, DIN, 0);
  transpose_bf16_kernel<<<dim3(DIN / 32, DIN / 32), t32x8, 0, stream>>>(W_aq, Wt_aq, DIN, DIN,
                                                                        DIN, DIN, 0);
  // W_s1 top block transposed (for W_ao@W_s1top GEMM)
  transpose_bf16_kernel<<<dim3(DMODEL / 32, DIN / 32), t32x8, 0, stream>>>(W_s1, Wts1top, DIN,
                                                                           DMODEL, DMODEL, DIN, 0);
  // W_s1 bottom block -> Wt_s1c cols [1024, 3072)
  transpose_bf16_kernel<<<dim3(DMODEL / 32, DMODEL / 32), t32x8, 0, stream>>>(
      W_s1 + (size_t)DIN * DMODEL, Wt_s1c, DMODEL, DMODEL, DMODEL, DIN + DMODEL, DIN);
  transpose_bf16_kernel<<<dim3(DMODEL / 32, DMODEL / 32), t32x8, 0, stream>>>(W_s2, Wt_s2, DMODEL,
                                                                              DMODEL, DMODEL,
                                                                              DMODEL, 0);
  transpose_bf16_kernel<<<dim3((DOUT + 31) / 32, NSYNC / 32), t32x8, 0, stream>>>(
      W_out, Wt_out, NSYNC, DOUT, DOUT, NSYNC, 0);
  conv_bf16_kernel<<<(NSYNC * DIN + 255) / 256, 256, 0, stream>>>(W_q, W_qb, NSYNC * DIN);
  conv_bf16_kernel<<<(DIN * DIN + 255) / 256, 256, 0, stream>>>(W_ao, W_ao_b, DIN * DIN);
  bqaq_kernel<<<4, 256, 0, stream>>>(b_q, b_aq, Wt_aq, b_qaq);
  bs1c_kernel<<<8, 256, 0, stream>>>(b_s1, b_ao, W_s1, b_s1c);
  hipMemcpyAsync(b_akav, b_ak, DIN * 4, hipMemcpyDeviceToDevice, stream);
  hipMemcpyAsync(b_akav + DIN, b_av, DIN * 4, hipMemcpyDeviceToDevice, stream);

  // ---- precompute ----
  gemm_big<0, float, float><<<dim3(DIN / 128, MS / 128), 256, 0, stream>>>(x, Wt_kv, b_kv, kvraw,
                                                                           (int)MS, DIN, F_);
  ln_kernel<__hip_bfloat16><<<(int)MS, 256, 0, stream>>>(kvraw, g_kv, be_kv, kv, DIN, DIN, 1);
  // kh|vh combined: N=2048 vs concat(Wt_ak, Wt_av), TRANSC=3 routes halves
  gemm_big<3, __hip_bfloat16, __hip_bfloat16><<<dim3(2 * DIN / 128, MS / 128), 256, 0, stream>>>(
      kv, Wt_akav, b_akav, kh, (int)MS, 2 * DIN, DIN);
  // Wt_qaq = (W_q @ W_aq)^T
  gemm_big<1, __hip_bfloat16, __hip_bfloat16><<<dim3(DIN / 128, NSYNC / 128), 256, 0, stream>>>(
      W_qb, Wt_aq, nullptr, Wt_qaq, NSYNC, DIN, DIN);
  // Wt_s1c cols [0,1024): (W_ao @ W_s1top)^T via TRANSC=1 with stride M=3072
  gemm_big<1, __hip_bfloat16, __hip_bfloat16><<<dim3(DMODEL / 128, DIN / 128), 256, 0, stream>>>(
      W_ao_b, Wts1top, nullptr, Wt_s1c, DIN + DMODEL, DMODEL, DIN);

  // ---- state init ----
  init_pre_kernel<<<(B_ * DMODEL + 255) / 256, 256, 0, stream>>>(init_state, pre);
  init_hist_kernel<<<(B_ * DMODEL * DMEM + 255) / 256, 256, 0, stream>>>(init_hist, histf);
  init_sync_kernel<<<(B_ * NSYNC + 255) / 256, 256, 0, stream>>>(
      init_state, decay_action, decay_out, idx_la, idx_ra, idx_lo, idx_ro, aA, bA, aO, bO,
      syncA0, rAv, rOv);
  qh0_kernel<<<B_, 256, 0, stream>>>(syncA0, Wt_qaq, b_qaq, qhb);

  // ---- tick loop: 7 kernels per tick, atomic-free ----
  for (int t = 0; t < TICKS; ++t) {
    // attention -> pre[:, :1024]
    attn_kernel<<<B_ * NH, 256, 0, stream>>>(qhb, kh, vh, pre);
    // s1 partials (K=3072, KS=8, kchunk 384) + reduce+gelu -> h1
    gemm_part<<<dim3(32, 8), 256, 0, stream>>>(pre, DIN + DMODEL, Wt_s1c, DIN + DMODEL, partial,
                                               DMODEL, 384);
    s1_red_kernel<<<512, 256, 0, stream>>>(partial, b_s1c, h1, 8);
    // s2 partials (K=2048, KS=8, kchunk 256) + reduce+LN -> hist slot 32+t
    gemm_part<<<dim3(32, 8), 256, 0, stream>>>(h1, DMODEL, Wt_s2, DMODEL, partial, DMODEL, 256);
    s2_red_ln_kernel<<<B_, 256, 0, stream>>>(partial, b_s2, g_s, be_s, histf, 8, t);
    nlm_kernel<<<DMODEL / 4, 256, 0, stream>>>(histf, W_n1, b_n1, W_n2, b_n2, nlmraw, t);
    final_kernel<<<B_, 256, 0, stream>>>(nlmraw, g_n, be_n, idx_la, idx_ra, idx_lo, idx_ro, rAv,
                                         rOv, aA, bA, aO, bO, pre, Wt_qaq, b_qaq, qhb, Wt_out,
                                         b_out, out, t);
  }
  (void)in_sizes; (void)n_in; (void)out_size; (void)ws_size;
}

// Round 16
// 2614.136 us; speedup vs baseline: 1.5487x; 1.5487x over previous
//
#include <hip/hip_runtime.h>
#include <hip/hip_bf16.h>

// ---------------------------------------------------------------------------
// CTM round 15: REVERT to the round-13 best-known configuration (2.615 ms).
// Round-14's qh-GEMV fusion into final_kernel regressed +90us/tick (64-block
// GEMV amplifies weight traffic 64x at 25% occupancy; likely spills). Lesson
// recorded; structure restored: 8-launch atomic-free tick loop, qh gemm_part
// + attention-fused reduce, merged kh|vh precompute GEMM, XCD-chunked swizzle.
// ---------------------------------------------------------------------------

#define B_ 64
#define S_ 512
#define F_ 1024
#define DMODEL 2048
#define DMEM 32
#define DIN 1024
#define NH 16
#define DH 64
#define DOUT 1000
#define NSYNC 512
#define TICKS 16
#define HNLM 32
#define HIST_W 48

typedef __attribute__((ext_vector_type(8))) short short8;
typedef __attribute__((ext_vector_type(4))) float f32x4;

__device__ inline void store_f(float* p, float v) { *p = v; }
__device__ inline void store_f(__hip_bfloat16* p, float v) { *p = __float2bfloat16(v); }

__device__ inline short f2bs(float f) {
  __hip_bfloat16 h = __float2bfloat16(f);
  return *reinterpret_cast<short*>(&h);
}

__device__ inline float bfs(short x) {
  return __uint_as_float(((unsigned)(unsigned short)x) << 16);
}

__device__ inline float gelu_f(float x) {
  float x3 = x * x * x;
  return 0.5f * x * (1.f + tanhf(0.7978845608028654f * (x + 0.044715f * x3)));
}

__device__ inline float bf_lo(unsigned v) { return __uint_as_float(v << 16); }
__device__ inline float bf_hi(unsigned v) { return __uint_as_float(v & 0xffff0000u); }

// ---------------- weight prep ----------------
// W (K,N) fp32 -> Wt rows n: Wt[n*ldw + koff + k] = W[k*N + n], zero-pad n>=N
__global__ __launch_bounds__(256) void transpose_bf16_kernel(const float* __restrict__ W,
                                                             __hip_bfloat16* __restrict__ Wt,
                                                             int K, int N, int Npad, int ldw,
                                                             int koff) {
  __shared__ float t[32][33];
  const int tx = threadIdx.x, ty = threadIdx.y;  // 32 x 8
  const int n0 = blockIdx.x * 32, k0 = blockIdx.y * 32;
#pragma unroll
  for (int i = 0; i < 4; i++) {
    int k = k0 + ty + i * 8;
    t[ty + i * 8][tx] = (k < K && n0 + tx < N) ? W[(size_t)k * N + n0 + tx] : 0.f;
  }
  __syncthreads();
#pragma unroll
  for (int i = 0; i < 4; i++) {
    int n = n0 + ty + i * 8;
    if (n < Npad && k0 + tx < K)
      Wt[(size_t)n * ldw + koff + k0 + tx] = __float2bfloat16(t[tx][ty + i * 8]);
  }
}

__global__ void conv_bf16_kernel(const float* __restrict__ src, __hip_bfloat16* __restrict__ dst,
                                 int n) {
  int i = blockIdx.x * 256 + threadIdx.x;
  if (i < n) dst[i] = __float2bfloat16(src[i]);
}

__global__ void bqaq_kernel(const float* __restrict__ b_q, const float* __restrict__ b_aq,
                            const __hip_bfloat16* __restrict__ Wt_aq, float* __restrict__ b_qaq) {
  int n = blockIdx.x * 256 + threadIdx.x;
  if (n >= DIN) return;
  const __hip_bfloat16* wr = Wt_aq + (size_t)n * DIN;
  float s = b_aq[n];
  for (int k = 0; k < DIN; k++) s += b_q[k] * __bfloat162float(wr[k]);
  b_qaq[n] = s;
}

// b_s1c[n] = b_s1[n] + sum_{k<1024} b_ao[k] * W_s1[k, n]   (n < 2048)
__global__ void bs1c_kernel(const float* __restrict__ b_s1, const float* __restrict__ b_ao,
                            const float* __restrict__ W_s1, float* __restrict__ b_s1c) {
  int n = blockIdx.x * 256 + threadIdx.x;
  if (n >= DMODEL) return;
  float s = b_s1[n];
  for (int k = 0; k < DIN; k++) s += b_ao[k] * W_s1[(size_t)k * DMODEL + n];
  b_s1c[n] = s;
}

// ---------------- big MFMA GEMM (precompute), XCD-chunked swizzle ----------
// TRANSC: 0 = row-major C[M,N]; 1 = C^T with row-stride M; 2 = attn layout;
//         3 = combined kh|vh attn layout (N=2048; col>=1024 -> vh region)
__device__ inline short8 load_chunk(const __hip_bfloat16* p) {
  return *reinterpret_cast<const short8*>(p);
}
__device__ inline short8 load_chunk(const float* p) {
  short8 r;
#pragma unroll
  for (int j = 0; j < 8; j++) r[j] = f2bs(p[j]);
  return r;
}

template <int TRANSC, typename TA, typename TC>
__global__ __launch_bounds__(256) void gemm_big(const TA* __restrict__ A,
                                                const __hip_bfloat16* __restrict__ Bt,
                                                const float* __restrict__ bias,
                                                TC* __restrict__ C, int M, int N, int K) {
  __shared__ short lsA[128 * 64];
  __shared__ short lsB[128 * 64];
  const int tid = threadIdx.x;
  const int l = tid & 63, w = tid >> 6;
  const int wr = (w >> 1) * 64, wc = (w & 1) * 64;
  const int nwg = gridDim.x * gridDim.y;
  const int flat = blockIdx.y * gridDim.x + blockIdx.x;
  const int wk = (flat & 7) * (nwg >> 3) + (flat >> 3);  // nwg % 8 == 0
  const int brow = (wk / gridDim.x) * 128, bcol = (wk % gridDim.x) * 128;
  f32x4 acc[4][4];
#pragma unroll
  for (int i = 0; i < 4; i++)
#pragma unroll
    for (int j = 0; j < 4; j++)
#pragma unroll
      for (int r = 0; r < 4; r++) acc[i][j][r] = 0.f;

  short8 ra[4], rb[4];
  auto gload = [&](int k0) {
#pragma unroll
    for (int q = 0; q < 4; q++) {
      int i = tid + q * 256;
      int row = i >> 3, c = i & 7;
      ra[q] = load_chunk(A + (size_t)(brow + row) * K + k0 + c * 8);
      rb[q] = load_chunk(Bt + (size_t)(bcol + row) * K + k0 + c * 8);
    }
  };
  auto lwrite = [&]() {
#pragma unroll
    for (int q = 0; q < 4; q++) {
      int i = tid + q * 256;
      int row = i >> 3, c = i & 7;
      int sw = c ^ (row & 7);
      *reinterpret_cast<short8*>(&lsA[row * 64 + sw * 8]) = ra[q];
      *reinterpret_cast<short8*>(&lsB[row * 64 + sw * 8]) = rb[q];
    }
  };
  gload(0);
  for (int k0 = 0; k0 < K; k0 += 64) {
    __syncthreads();
    lwrite();
    if (k0 + 64 < K) gload(k0 + 64);
    __syncthreads();
#pragma unroll
    for (int ks = 0; ks < 2; ks++) {
      short8 af[4], bfv[4];
#pragma unroll
      for (int mi = 0; mi < 4; mi++) {
        int row = wr + mi * 16 + (l & 15);
        int c = ks * 4 + (l >> 4);
        af[mi] = *reinterpret_cast<const short8*>(&lsA[row * 64 + (c ^ (row & 7)) * 8]);
      }
#pragma unroll
      for (int ni = 0; ni < 4; ni++) {
        int row = wc + ni * 16 + (l & 15);
        int c = ks * 4 + (l >> 4);
        bfv[ni] = *reinterpret_cast<const short8*>(&lsB[row * 64 + (c ^ (row & 7)) * 8]);
      }
#pragma unroll
      for (int mi = 0; mi < 4; mi++)
#pragma unroll
        for (int ni = 0; ni < 4; ni++)
          acc[mi][ni] =
              __builtin_amdgcn_mfma_f32_16x16x32_bf16(af[mi], bfv[ni], acc[mi][ni], 0, 0, 0);
    }
  }
#pragma unroll
  for (int mi = 0; mi < 4; mi++)
#pragma unroll
    for (int ni = 0; ni < 4; ni++)
#pragma unroll
      for (int r = 0; r < 4; r++) {
        int row = brow + wr + mi * 16 + (l >> 4) * 4 + r;
        int col = bcol + wc + ni * 16 + (l & 15);
        float v = acc[mi][ni][r];
        if (bias) v += bias[col];
        if (TRANSC == 1) {
          store_f(&C[(size_t)col * M + row], v);
        } else if (TRANSC == 2) {
          int bb = row >> 9, s = row & 511, hh = col >> 6, dd = col & 63;
          store_f(&C[(((size_t)(bb * 16 + hh) * 512) + s) * 64 + dd], v);
        } else if (TRANSC == 3) {
          int bb = row >> 9, s = row & 511, hh2 = col >> 6, dd = col & 63;
          size_t base = (hh2 >= 16) ? (size_t)B_ * S_ * DIN : 0;  // vh after kh
          store_f(&C[base + (((size_t)(bb * 16 + (hh2 & 15)) * 512) + s) * 64 + dd], v);
        } else {
          store_f(&C[(size_t)row * N + col], v);
        }
      }
}

// ---------------- LayerNorm (strided/typed output) ----------------
template <typename TOUT>
__global__ __launch_bounds__(256) void ln_kernel(const float* __restrict__ x,
                                                 const float* __restrict__ g,
                                                 const float* __restrict__ be,
                                                 TOUT* __restrict__ out, int C,
                                                 size_t row_stride, int col_stride) {
  const int row = blockIdx.x;
  const int tid = threadIdx.x;
  const float* xr = x + (size_t)row * C;
  float s = 0.f, s2 = 0.f;
  for (int c = tid; c < C; c += 256) {
    float v = xr[c];
    s += v;
    s2 += v * v;
  }
  __shared__ float r1[256], r2[256];
  r1[tid] = s;
  r2[tid] = s2;
  __syncthreads();
  for (int st = 128; st > 0; st >>= 1) {
    if (tid < st) {
      r1[tid] += r1[tid + st];
      r2[tid] += r2[tid + st];
    }
    __syncthreads();
  }
  float mean = r1[0] / C;
  float var = r2[0] / C - mean * mean;
  float inv = 1.0f / sqrtf(var + 1e-5f);
  for (int c = tid; c < C; c += 256) {
    float v = (xr[c] - mean) * inv * g[c] + be[c];
    store_f(&out[(size_t)row * row_stride + (size_t)c * col_stride], v);
  }
}

// ---------------- init kernels ----------------
__global__ void init_pre_kernel(const float* __restrict__ init_state,
                                __hip_bfloat16* __restrict__ pre) {
  int i = blockIdx.x * 256 + threadIdx.x;
  if (i >= B_ * DMODEL) return;
  int b = i >> 11, j = i & (DMODEL - 1);
  pre[(size_t)b * 3072 + DIN + j] = __float2bfloat16(init_state[j]);
}

__global__ void init_hist_kernel(const float* __restrict__ init_hist, float* __restrict__ hist) {
  int i = blockIdx.x * 256 + threadIdx.x;
  if (i >= B_ * DMODEL * DMEM) return;
  int m = i & (DMEM - 1);
  int bd = i >> 5;
  int d = bd & (DMODEL - 1);
  hist[(size_t)bd * HIST_W + m] = init_hist[d * DMEM + m];
}

__global__ void init_sync_kernel(const float* __restrict__ init_state,
                                 const float* __restrict__ decay_action,
                                 const float* __restrict__ decay_out,
                                 const int* __restrict__ la, const int* __restrict__ ra,
                                 const int* __restrict__ lo, const int* __restrict__ ro,
                                 float* __restrict__ aA, float* __restrict__ bA,
                                 float* __restrict__ aO, float* __restrict__ bO,
                                 __hip_bfloat16* __restrict__ syncA, float* __restrict__ rAv,
                                 float* __restrict__ rOv) {
  int i = blockIdx.x * 256 + threadIdx.x;
  if (i >= B_ * NSYNC) return;
  int j = i & (NSYNC - 1);
  if (i < NSYNC) {
    rAv[i] = expf(-fminf(fmaxf(decay_action[i], 0.f), 15.f));
    rOv[i] = expf(-fminf(fmaxf(decay_out[i], 0.f), 15.f));
  }
  float pA = init_state[la[j]] * init_state[ra[j]];
  aA[i] = pA;
  bA[i] = 1.f;
  syncA[i] = __float2bfloat16(pA);  // pA / sqrt(1)
  aO[i] = init_state[lo[j]] * init_state[ro[j]];
  bO[i] = 1.f;
}

// ---------------- 64xN-tile MFMA matmul body (tick GEMMs) ----------------
template <typename EPI>
__device__ __forceinline__ void mm_tile64(const __hip_bfloat16* __restrict__ A, int lda,
                                          const __hip_bfloat16* __restrict__ Bt, int ldb,
                                          int bcol, int kb, int kchunk, int tid, short* lsA,
                                          short* lsB, EPI epi) {
  const int l = tid & 63, w = tid >> 6;
  f32x4 acc[4];
#pragma unroll
  for (int i = 0; i < 4; i++)
#pragma unroll
    for (int r = 0; r < 4; r++) acc[i][r] = 0.f;
  short8 ra[2], rb[2];
  auto gload = [&](int k0) {
#pragma unroll
    for (int q = 0; q < 2; q++) {
      int i = tid + q * 256;
      int row = i >> 3, c = i & 7;
      ra[q] = *reinterpret_cast<const short8*>(A + (size_t)row * lda + k0 + c * 8);
      rb[q] = *reinterpret_cast<const short8*>(Bt + (size_t)(bcol + row) * ldb + k0 + c * 8);
    }
  };
  auto lwrite = [&]() {
#pragma unroll
    for (int q = 0; q < 2; q++) {
      int i = tid + q * 256;
      int row = i >> 3, c = i & 7;
      int sw = c ^ (row & 7);
      *reinterpret_cast<short8*>(&lsA[row * 64 + sw * 8]) = ra[q];
      *reinterpret_cast<short8*>(&lsB[row * 64 + sw * 8]) = rb[q];
    }
  };
  gload(kb);
  for (int k0 = kb; k0 < kb + kchunk; k0 += 64) {
    __syncthreads();
    lwrite();
    if (k0 + 64 < kb + kchunk) gload(k0 + 64);
    __syncthreads();
#pragma unroll
    for (int ks = 0; ks < 2; ks++) {
      int rowa = w * 16 + (l & 15);
      int c = ks * 4 + (l >> 4);
      short8 af = *reinterpret_cast<const short8*>(&lsA[rowa * 64 + (c ^ (rowa & 7)) * 8]);
#pragma unroll
      for (int ni = 0; ni < 4; ni++) {
        int rowb = ni * 16 + (l & 15);
        short8 bfv = *reinterpret_cast<const short8*>(&lsB[rowb * 64 + (c ^ (rowb & 7)) * 8]);
        acc[ni] = __builtin_amdgcn_mfma_f32_16x16x32_bf16(af, bfv, acc[ni], 0, 0, 0);
      }
    }
  }
#pragma unroll
  for (int ni = 0; ni < 4; ni++)
#pragma unroll
    for (int r = 0; r < 4; r++) {
      int m = w * 16 + (l >> 4) * 4 + r;
      int n = bcol + ni * 16 + (l & 15);
      epi(m, n, acc[ni][r]);
    }
}

// ---------------- split-K partial GEMM (atomic-free) ----------------
__global__ __launch_bounds__(256) void gemm_part(const __hip_bfloat16* __restrict__ A, int lda,
                                                 const __hip_bfloat16* __restrict__ Bt, int ldb,
                                                 float* __restrict__ part, int N, int kchunk) {
  __shared__ short lsA[64 * 64];
  __shared__ short lsB[64 * 64];
  const int tid = threadIdx.x;
  const int nt = blockIdx.x, ks = blockIdx.y;
  mm_tile64(A, lda, Bt, ldb, nt * 64, ks * kchunk, kchunk, tid, lsA, lsB,
            [&](int m, int n, float v) { part[((size_t)(ks * 64 + m)) * N + n] = v; });
}

// reduce(KS) + bias + gelu -> h1 (bf16)
__global__ void s1_red_kernel(const float* __restrict__ part, const float* __restrict__ bias,
                              __hip_bfloat16* __restrict__ h1, int KS) {
  int i = blockIdx.x * 256 + threadIdx.x;  // 64*2048
  int m = i >> 11, n = i & 2047;
  float s = bias[n];
  for (int k = 0; k < KS; k++) s += part[((size_t)(k * 64 + m)) * DMODEL + n];
  h1[(size_t)m * DMODEL + n] = __float2bfloat16(gelu_f(s));
}

// reduce(KS) + bias + LayerNorm -> hist slot 32+t (one block per batch row)
__global__ __launch_bounds__(256) void s2_red_ln_kernel(const float* __restrict__ part,
                                                        const float* __restrict__ bias,
                                                        const float* __restrict__ g,
                                                        const float* __restrict__ be,
                                                        float* __restrict__ hist, int KS, int t) {
  __shared__ float r1[256], r2[256];
  const int b = blockIdx.x;
  const int tid = threadIdx.x;
  float v8[8];
  float s = 0.f, s2 = 0.f;
#pragma unroll
  for (int i = 0; i < 8; i++) {
    int n = tid + i * 256;
    float x = bias[n];
    for (int k = 0; k < KS; k++) x += part[((size_t)(k * 64 + b)) * DMODEL + n];
    v8[i] = x;
    s += x;
    s2 += x * x;
  }
  r1[tid] = s;
  r2[tid] = s2;
  __syncthreads();
  for (int st = 128; st > 0; st >>= 1) {
    if (tid < st) {
      r1[tid] += r1[tid + st];
      r2[tid] += r2[tid + st];
    }
    __syncthreads();
  }
  float mean = r1[0] / DMODEL;
  float var = r2[0] / DMODEL - mean * mean;
  float inv = 1.f / sqrtf(var + 1e-5f);
#pragma unroll
  for (int i = 0; i < 8; i++) {
    int n = tid + i * 256;
    float pa = (v8[i] - mean) * inv * g[n] + be[n];
    hist[((size_t)b * DMODEL + n) * HIST_W + 32 + t] = pa;
  }
}

// ---------------- attention (head-major K/V; fused qh split-K reduce) -------
// writes directly into pre[:, :1024]
__global__ __launch_bounds__(256) void attn_kernel(const float* __restrict__ qpart,
                                                   const float* __restrict__ b_qaq,
                                                   const __hip_bfloat16* __restrict__ kh,
                                                   const __hip_bfloat16* __restrict__ vh,
                                                   __hip_bfloat16* __restrict__ pre) {
  __shared__ float qs[64];
  __shared__ float wv[512];
  __shared__ float red[256];
  __shared__ float red2[2048];
  const int u = blockIdx.x;
  const int b = u >> 4, h = u & (NH - 1);
  const int tid = threadIdx.x;
  const __hip_bfloat16* Kp = kh + (size_t)u * (S_ * DH);
  const __hip_bfloat16* Vp = vh + (size_t)u * (S_ * DH);
  if (tid < DH) {
    int n = h * DH + tid;
    float s = b_qaq[n];
#pragma unroll
    for (int ks = 0; ks < 4; ks++) s += qpart[((size_t)(ks * 64 + b)) * DIN + n];
    qs[tid] = s;
  }
  __syncthreads();
  float sc[2];
#pragma unroll
  for (int r = 0; r < 2; ++r) {
    int s = tid + r * 256;
    const short8* kp = reinterpret_cast<const short8*>(Kp + (size_t)s * DH);
    float accv = 0.f;
#pragma unroll
    for (int q = 0; q < 8; ++q) {
      short8 kk = kp[q];
#pragma unroll
      for (int j = 0; j < 8; ++j) accv += qs[q * 8 + j] * bfs(kk[j]);
    }
    sc[r] = accv * 0.125f;
  }
  red[tid] = fmaxf(sc[0], sc[1]);
  __syncthreads();
  for (int st = 128; st > 0; st >>= 1) {
    if (tid < st) red[tid] = fmaxf(red[tid], red[tid + st]);
    __syncthreads();
  }
  const float mx = red[0];
  __syncthreads();
  float e0 = expf(sc[0] - mx), e1 = expf(sc[1] - mx);
  wv[tid] = e0;
  wv[tid + 256] = e1;
  red[tid] = e0 + e1;
  __syncthreads();
  for (int st = 128; st > 0; st >>= 1) {
    if (tid < st) red[tid] += red[tid + st];
    __syncthreads();
  }
  const float invZ = 1.f / red[0];
  __syncthreads();
  const int d8 = tid & 7, sg = tid >> 3;
  float pacc[8];
#pragma unroll
  for (int j = 0; j < 8; ++j) pacc[j] = 0.f;
  for (int s = sg; s < S_; s += 32) {
    float wgt = wv[s];
    short8 vvv = *reinterpret_cast<const short8*>(Vp + (size_t)s * DH + d8 * 8);
#pragma unroll
    for (int j = 0; j < 8; ++j) pacc[j] += wgt * bfs(vvv[j]);
  }
#pragma unroll
  for (int j = 0; j < 8; ++j) red2[sg * 64 + d8 * 8 + j] = pacc[j];
  __syncthreads();
  if (tid < DH) {
    float r = 0.f;
#pragma unroll
    for (int g2 = 0; g2 < 32; ++g2) r += red2[g2 * 64 + tid];
    pre[(size_t)b * 3072 + h * DH + tid] = __float2bfloat16(r * invZ);
  }
}

// ---------------- per-neuron NLM ----------------
__global__ __launch_bounds__(256) void nlm_kernel(const float* __restrict__ hist,
                                                  const float* __restrict__ W1,
                                                  const float* __restrict__ b1,
                                                  const float* __restrict__ W2,
                                                  const float* __restrict__ b2,
                                                  float* __restrict__ out, int t) {
  __shared__ float w1s[4096];
  __shared__ float b1s[128];
  const int tid = threadIdx.x;
  const int d0 = blockIdx.x * 4;
  for (int i = tid; i < 4096; i += 256) w1s[i] = W1[(size_t)d0 * 1024 + i];
  if (tid < 128) b1s[tid] = b1[d0 * 32 + tid];
  __syncthreads();
  const int b = tid & 63, dsub = tid >> 6;
  const int d = d0 + dsub;
  const float* hw = hist + ((size_t)(b * DMODEL + d)) * HIST_W + (t + 1);
  float win[DMEM];
#pragma unroll
  for (int m = 0; m < DMEM; ++m) win[m] = hw[m];
  const float* w1 = w1s + dsub * 1024;
  const float* bb = b1s + dsub * 32;
  const float* w2 = W2 + d * HNLM;
  float acc = 0.f;
  for (int h = 0; h < HNLM; ++h) {
    float s = bb[h];
#pragma unroll
    for (int m = 0; m < DMEM; ++m) s += win[m] * w1[m * HNLM + h];
    acc += fmaxf(s, 0.f) * w2[h];
  }
  out[(size_t)b * DMODEL + d] = acc + b2[d];
}

// ---------------- final fused kernel: LN -> sync updates -> pre pack ->
//   coalesced out-head GEMV + entropy. One block per batch b.
__global__ __launch_bounds__(256) void final_kernel(
    const float* __restrict__ nlmraw, const float* __restrict__ g_n,
    const float* __restrict__ be_n, const int* __restrict__ la, const int* __restrict__ ra,
    const int* __restrict__ lo, const int* __restrict__ ro, const float* __restrict__ rAv,
    const float* __restrict__ rOv, float* __restrict__ aA, float* __restrict__ bA,
    float* __restrict__ aO, float* __restrict__ bO, __hip_bfloat16* __restrict__ syncA,
    __hip_bfloat16* __restrict__ pre, const __hip_bfloat16* __restrict__ Wt_out,
    const float* __restrict__ b_out, float* __restrict__ outp, int t) {
  __shared__ float arow[2048];
  __shared__ float so_p[520];  // syncO with +1-per-64 pad (bank spread)
  __shared__ float pv[1024];
  __shared__ float red[256], red2[256];
  const int b = blockIdx.x;
  const int tid = threadIdx.x;
  const float* xr = nlmraw + (size_t)b * DMODEL;
  float xv[8];
  float s = 0.f, s2 = 0.f;
#pragma unroll
  for (int i = 0; i < 8; i++) {
    float x = xr[tid + i * 256];
    xv[i] = x;
    s += x;
    s2 += x * x;
  }
  red[tid] = s;
  red2[tid] = s2;
  __syncthreads();
  for (int st = 128; st > 0; st >>= 1) {
    if (tid < st) {
      red[tid] += red[tid + st];
      red2[tid] += red2[tid + st];
    }
    __syncthreads();
  }
  float mean = red[0] / DMODEL;
  float var = red2[0] / DMODEL - mean * mean;
  float inv = 1.f / sqrtf(var + 1e-5f);
  __syncthreads();
#pragma unroll
  for (int i = 0; i < 8; i++) {
    int n = tid + i * 256;
    float av = (xv[i] - mean) * inv * g_n[n] + be_n[n];
    arow[n] = av;
    pre[(size_t)b * 3072 + DIN + n] = __float2bfloat16(av);  // act for tick t+1
  }
  __syncthreads();
  for (int j = tid; j < NSYNC; j += 256) {
    size_t idx = (size_t)b * NSYNC + j;
    float pA = arow[la[j]] * arow[ra[j]];
    float r = rAv[j];
    float av2 = r * aA[idx] + pA, bv2 = r * bA[idx] + 1.f;
    aA[idx] = av2;
    bA[idx] = bv2;
    syncA[idx] = __float2bfloat16(av2 / sqrtf(bv2));  // syncA (t+1) -> global
    float pO = arow[lo[j]] * arow[ro[j]];
    float ro2 = rOv[j];
    float av3 = ro2 * aO[idx] + pO, bv3 = ro2 * bO[idx] + 1.f;
    aO[idx] = av3;
    bO[idx] = bv3;
    so_p[j + (j >> 6)] = av3 / sqrtf(bv3);  // syncO (t) in padded LDS
  }
  __syncthreads();
  // out head: 8 lanes per output row; per q, the 8 lanes read one contiguous
  // 128B short8 chunk of row n (fully-consumed lines); shfl-xor 3-step reduce.
  const int lk = tid & 7;   // k-slice within row
  const int rg = tid >> 3;  // row-group 0..31
  for (int it = 0; it < 32; ++it) {
    int n = it * 32 + rg;
    float sacc = 0.f;
    if (n < DOUT) {
      const short8* wr8 = reinterpret_cast<const short8*>(Wt_out + (size_t)n * NSYNC);
#pragma unroll
      for (int q = 0; q < 8; ++q) {
        short8 w8 = wr8[q * 8 + lk];
#pragma unroll
        for (int j = 0; j < 8; ++j) sacc += so_p[q * 65 + lk * 8 + j] * bfs(w8[j]);
      }
    }
    sacc += __shfl_xor(sacc, 1);
    sacc += __shfl_xor(sacc, 2);
    sacc += __shfl_xor(sacc, 4);
    if (lk == 0 && n < DOUT) pv[n] = sacc + b_out[n];
  }
  __syncthreads();
  float m = -1e30f;
  for (int o = tid; o < DOUT; o += 256) m = fmaxf(m, pv[o]);
  red[tid] = m;
  __syncthreads();
  for (int st = 128; st > 0; st >>= 1) {
    if (tid < st) red[tid] = fmaxf(red[tid], red[tid + st]);
    __syncthreads();
  }
  m = red[0];
  __syncthreads();
  float z = 0.f, s1 = 0.f;
  for (int o = tid; o < DOUT; o += 256) {
    float wv2 = pv[o] - m;
    float e = expf(wv2);
    z += e;
    s1 += e * wv2;
  }
  red[tid] = z;
  __syncthreads();
  for (int st = 128; st > 0; st >>= 1) {
    if (tid < st) red[tid] += red[tid + st];
    __syncthreads();
  }
  const float Z = red[0];
  __syncthreads();
  red[tid] = s1;
  __syncthreads();
  for (int st = 128; st > 0; st >>= 1) {
    if (tid < st) red[tid] += red[tid + st];
    __syncthreads();
  }
  const float S1 = red[0];
  const float ne = -(S1 / Z - logf(Z)) / 6.907755278982137f;
  for (int o = tid; o < DOUT; o += 256) outp[((size_t)b * DOUT + o) * TICKS + t] = pv[o];
  if (tid == 0) {
    float* c = outp + (size_t)B_ * DOUT * TICKS;
    c[b * 2 * TICKS + t] = ne;
    c[b * 2 * TICKS + TICKS + t] = 1.f - ne;
  }
}

// ---------------------------------------------------------------------------
extern "C" void kernel_launch(void* const* d_in, const int* in_sizes, int n_in,
                              void* d_out, int out_size, void* d_ws, size_t ws_size,
                              hipStream_t stream) {
  const float* x = (const float*)d_in[0];
  const float* W_kv = (const float*)d_in[1];
  const float* b_kv = (const float*)d_in[2];
  const float* g_kv = (const float*)d_in[3];
  const float* be_kv = (const float*)d_in[4];
  const float* W_q = (const float*)d_in[5];
  const float* b_q = (const float*)d_in[6];
  const float* W_aq = (const float*)d_in[7];
  const float* b_aq = (const float*)d_in[8];
  const float* W_ak = (const float*)d_in[9];
  const float* b_ak = (const float*)d_in[10];
  const float* W_av = (const float*)d_in[11];
  const float* b_av = (const float*)d_in[12];
  const float* W_ao = (const float*)d_in[13];
  const float* b_ao = (const float*)d_in[14];
  const float* W_s1 = (const float*)d_in[15];
  const float* b_s1 = (const float*)d_in[16];
  const float* W_s2 = (const float*)d_in[17];
  const float* b_s2 = (const float*)d_in[18];
  const float* g_s = (const float*)d_in[19];
  const float* be_s = (const float*)d_in[20];
  const float* W_n1 = (const float*)d_in[21];
  const float* b_n1 = (const float*)d_in[22];
  const float* W_n2 = (const float*)d_in[23];
  const float* b_n2 = (const float*)d_in[24];
  const float* g_n = (const float*)d_in[25];
  const float* be_n = (const float*)d_in[26];
  const float* init_state = (const float*)d_in[27];
  const float* init_hist = (const float*)d_in[28];
  const float* decay_action = (const float*)d_in[29];
  const float* decay_out = (const float*)d_in[30];
  const float* W_out = (const float*)d_in[31];
  const float* b_out = (const float*)d_in[32];
  const int* idx_la = (const int*)d_in[33];
  const int* idx_ra = (const int*)d_in[34];
  const int* idx_lo = (const int*)d_in[35];
  const int* idx_ro = (const int*)d_in[36];
  float* out = (float*)d_out;

  // ---- workspace carve ----
  char* wsb = (char*)d_ws;
  size_t off = 0;
  auto alloc = [&](size_t bytes) -> char* {
    char* p = wsb + off;
    off += (bytes + 255) & ~(size_t)255;
    return p;
  };
  const size_t MS = (size_t)B_ * S_;  // 32768
  char* regionA = alloc(MS * DIN * 4);  // kvraw fp32; later kh+vh bf16 (head-major)
  __hip_bfloat16* kv = (__hip_bfloat16*)alloc(MS * DIN * 2);
  float* histf = (float*)alloc((size_t)B_ * DMODEL * HIST_W * 4);
  __hip_bfloat16* Wt_kv = (__hip_bfloat16*)alloc((size_t)DIN * F_ * 2);
  __hip_bfloat16* Wt_akav = (__hip_bfloat16*)alloc((size_t)2 * DIN * DIN * 2);  // concat ak|av
  __hip_bfloat16* Wt_aq = (__hip_bfloat16*)alloc((size_t)DIN * DIN * 2);
  __hip_bfloat16* W_ao_b = (__hip_bfloat16*)alloc((size_t)DIN * DIN * 2);
  __hip_bfloat16* W_qb = (__hip_bfloat16*)alloc((size_t)NSYNC * DIN * 2);
  __hip_bfloat16* Wt_qaq = (__hip_bfloat16*)alloc((size_t)DIN * NSYNC * 2);
  __hip_bfloat16* Wts1top = (__hip_bfloat16*)alloc((size_t)DMODEL * DIN * 2);
  __hip_bfloat16* Wt_s1c = (__hip_bfloat16*)alloc((size_t)DMODEL * (DIN + DMODEL) * 2);
  __hip_bfloat16* Wt_s2 = (__hip_bfloat16*)alloc((size_t)DMODEL * DMODEL * 2);
  __hip_bfloat16* Wt_out = (__hip_bfloat16*)alloc((size_t)DOUT * NSYNC * 2);
  float* b_qaq = (float*)alloc(DIN * 4);
  float* b_s1c = (float*)alloc(DMODEL * 4);
  float* b_akav = (float*)alloc((size_t)2 * DIN * 4);
  float* partial = (float*)alloc((size_t)8 * 64 * DMODEL * 4);
  float* aA = (float*)alloc((size_t)B_ * NSYNC * 4);
  float* bA = (float*)alloc((size_t)B_ * NSYNC * 4);
  float* aO = (float*)alloc((size_t)B_ * NSYNC * 4);
  float* bO = (float*)alloc((size_t)B_ * NSYNC * 4);
  __hip_bfloat16* syncA = (__hip_bfloat16*)alloc((size_t)B_ * NSYNC * 2);
  __hip_bfloat16* pre = (__hip_bfloat16*)alloc((size_t)B_ * (DIN + DMODEL) * 2);
  __hip_bfloat16* h1 = (__hip_bfloat16*)alloc((size_t)B_ * DMODEL * 2);
  float* nlmraw = (float*)alloc((size_t)B_ * DMODEL * 4);
  float* rAv = (float*)alloc(NSYNC * 4);
  float* rOv = (float*)alloc(NSYNC * 4);

  float* kvraw = (float*)regionA;
  __hip_bfloat16* kh = (__hip_bfloat16*)regionA;                   // [b][h][s][d]
  __hip_bfloat16* vh = (__hip_bfloat16*)(regionA + MS * DIN * 2);  // [b][h][s][d]
  __hip_bfloat16* Wt_ak = Wt_akav;                                 // rows [0,1024)
  __hip_bfloat16* Wt_av = Wt_akav + (size_t)DIN * DIN;             // rows [1024,2048)

  dim3 t32x8(32, 8);
  // ---- weight prep ----
  transpose_bf16_kernel<<<dim3(F_ / 32, DIN / 32), t32x8, 0, stream>>>(W_kv, Wt_kv, F_, DIN, DIN,
                                                                       F_, 0);
  transpose_bf16_kernel<<<dim3(DIN / 32, DIN / 32), t32x8, 0, stream>>>(W_ak, Wt_ak, DIN, DIN,
                                                                        DIN, DIN, 0);
  transpose_bf16_kernel<<<dim3(DIN / 32, DIN / 32), t32x8, 0, stream>>>(W_av, Wt_av, DIN, DIN,
                                                                        DIN, DIN, 0);
  transpose_bf16_kernel<<<dim3(DIN / 32, DIN / 32), t32x8, 0, stream>>>(W_aq, Wt_aq, DIN, DIN,
                                                                        DIN, DIN, 0);
  // W_s1 top block transposed (for W_ao@W_s1top GEMM)
  transpose_bf16_kernel<<<dim3(DMODEL / 32, DIN / 32), t32x8, 0, stream>>>(W_s1, Wts1top, DIN,
                                                                           DMODEL, DMODEL, DIN, 0);
  // W_s1 bottom block -> Wt_s1c cols [1024, 3072)
  transpose_bf16_kernel<<<dim3(DMODEL / 32, DMODEL / 32), t32x8, 0, stream>>>(
      W_s1 + (size_t)DIN * DMODEL, Wt_s1c, DMODEL, DMODEL, DMODEL, DIN + DMODEL, DIN);
  transpose_bf16_kernel<<<dim3(DMODEL / 32, DMODEL / 32), t32x8, 0, stream>>>(W_s2, Wt_s2, DMODEL,
                                                                              DMODEL, DMODEL,
                                                                              DMODEL, 0);
  transpose_bf16_kernel<<<dim3((DOUT + 31) / 32, NSYNC / 32), t32x8, 0, stream>>>(
      W_out, Wt_out, NSYNC, DOUT, DOUT, NSYNC, 0);
  conv_bf16_kernel<<<(NSYNC * DIN + 255) / 256, 256, 0, stream>>>(W_q, W_qb, NSYNC * DIN);
  conv_bf16_kernel<<<(DIN * DIN + 255) / 256, 256, 0, stream>>>(W_ao, W_ao_b, DIN * DIN);
  bqaq_kernel<<<4, 256, 0, stream>>>(b_q, b_aq, Wt_aq, b_qaq);
  bs1c_kernel<<<8, 256, 0, stream>>>(b_s1, b_ao, W_s1, b_s1c);
  hipMemcpyAsync(b_akav, b_ak, DIN * 4, hipMemcpyDeviceToDevice, stream);
  hipMemcpyAsync(b_akav + DIN, b_av, DIN * 4, hipMemcpyDeviceToDevice, stream);

  // ---- precompute ----
  gemm_big<0, float, float><<<dim3(DIN / 128, MS / 128), 256, 0, stream>>>(x, Wt_kv, b_kv, kvraw,
                                                                           (int)MS, DIN, F_);
  ln_kernel<__hip_bfloat16><<<(int)MS, 256, 0, stream>>>(kvraw, g_kv, be_kv, kv, DIN, DIN, 1);
  // kh|vh combined: N=2048 vs concat(Wt_ak, Wt_av), TRANSC=3 routes halves
  gemm_big<3, __hip_bfloat16, __hip_bfloat16><<<dim3(2 * DIN / 128, MS / 128), 256, 0, stream>>>(
      kv, Wt_akav, b_akav, kh, (int)MS, 2 * DIN, DIN);
  // Wt_qaq = (W_q @ W_aq)^T
  gemm_big<1, __hip_bfloat16, __hip_bfloat16><<<dim3(DIN / 128, NSYNC / 128), 256, 0, stream>>>(
      W_qb, Wt_aq, nullptr, Wt_qaq, NSYNC, DIN, DIN);
  // Wt_s1c cols [0,1024): (W_ao @ W_s1top)^T via TRANSC=1 with stride M=3072
  gemm_big<1, __hip_bfloat16, __hip_bfloat16><<<dim3(DMODEL / 128, DIN / 128), 256, 0, stream>>>(
      W_ao_b, Wts1top, nullptr, Wt_s1c, DIN + DMODEL, DMODEL, DIN);

  // ---- state init ----
  init_pre_kernel<<<(B_ * DMODEL + 255) / 256, 256, 0, stream>>>(init_state, pre);
  init_hist_kernel<<<(B_ * DMODEL * DMEM + 255) / 256, 256, 0, stream>>>(init_hist, histf);
  init_sync_kernel<<<(B_ * NSYNC + 255) / 256, 256, 0, stream>>>(
      init_state, decay_action, decay_out, idx_la, idx_ra, idx_lo, idx_ro, aA, bA, aO, bO, syncA,
      rAv, rOv);

  // ---- tick loop: 8 kernels per tick, atomic-free ----
  for (int t = 0; t < TICKS; ++t) {
    // qh partials (K=512, KS=4, kchunk 128)
    gemm_part<<<dim3(16, 4), 256, 0, stream>>>(syncA, NSYNC, Wt_qaq, NSYNC, partial, DIN, 128);
    // attention (+fused qh reduce) -> pre[:, :1024]
    attn_kernel<<<B_ * NH, 256, 0, stream>>>(partial, b_qaq, kh, vh, pre);
    // s1 partials (K=3072, KS=8, kchunk 384) + reduce+gelu -> h1
    gemm_part<<<dim3(32, 8), 256, 0, stream>>>(pre, DIN + DMODEL, Wt_s1c, DIN + DMODEL, partial,
                                               DMODEL, 384);
    s1_red_kernel<<<512, 256, 0, stream>>>(partial, b_s1c, h1, 8);
    // s2 partials (K=2048, KS=8, kchunk 256) + reduce+LN -> hist slot 32+t
    gemm_part<<<dim3(32, 8), 256, 0, stream>>>(h1, DMODEL, Wt_s2, DMODEL, partial, DMODEL, 256);
    s2_red_ln_kernel<<<B_, 256, 0, stream>>>(partial, b_s2, g_s, be_s, histf, 8, t);
    nlm_kernel<<<DMODEL / 4, 256, 0, stream>>>(histf, W_n1, b_n1, W_n2, b_n2, nlmraw, t);
    final_kernel<<<B_, 256, 0, stream>>>(nlmraw, g_n, be_n, idx_la, idx_ra, idx_lo, idx_ro, rAv,
                                         rOv, aA, bA, aO, bO, syncA, pre, Wt_out, b_out, out, t);
  }
  (void)in_sizes; (void)n_in; (void)out_size; (void)ws_size;
}

// Round 17
// 2583.280 us; speedup vs baseline: 1.5672x; 1.0119x over previous
//
#include <hip/hip_runtime.h>
#include <hip/hip_bf16.h>

// ---------------------------------------------------------------------------
// CTM round 16: fix occupancy-starved weight-product GEMMs.
// Profile showed W_qaq (32 blocks) and W_ao@W_s1top (128 blocks) each cost
// ~196us -- same as the 69/137-GFLOP data GEMMs -- because 128^2 tiles give
// only 32/128 blocks on 256 CUs with a serial K loop. Replaced with
// gemm_wt64: 64x64 tiles over full K (mm_tile64 body), 128/512 blocks,
// transposed epilogue. Everything else identical to the 2.614 ms baseline.
// ---------------------------------------------------------------------------

#define B_ 64
#define S_ 512
#define F_ 1024
#define DMODEL 2048
#define DMEM 32
#define DIN 1024
#define NH 16
#define DH 64
#define DOUT 1000
#define NSYNC 512
#define TICKS 16
#define HNLM 32
#define HIST_W 48

typedef __attribute__((ext_vector_type(8))) short short8;
typedef __attribute__((ext_vector_type(4))) float f32x4;

__device__ inline void store_f(float* p, float v) { *p = v; }
__device__ inline void store_f(__hip_bfloat16* p, float v) { *p = __float2bfloat16(v); }

__device__ inline short f2bs(float f) {
  __hip_bfloat16 h = __float2bfloat16(f);
  return *reinterpret_cast<short*>(&h);
}

__device__ inline float bfs(short x) {
  return __uint_as_float(((unsigned)(unsigned short)x) << 16);
}

__device__ inline float gelu_f(float x) {
  float x3 = x * x * x;
  return 0.5f * x * (1.f + tanhf(0.7978845608028654f * (x + 0.044715f * x3)));
}

__device__ inline float bf_lo(unsigned v) { return __uint_as_float(v << 16); }
__device__ inline float bf_hi(unsigned v) { return __uint_as_float(v & 0xffff0000u); }

// ---------------- weight prep ----------------
// W (K,N) fp32 -> Wt rows n: Wt[n*ldw + koff + k] = W[k*N + n], zero-pad n>=N
__global__ __launch_bounds__(256) void transpose_bf16_kernel(const float* __restrict__ W,
                                                             __hip_bfloat16* __restrict__ Wt,
                                                             int K, int N, int Npad, int ldw,
                                                             int koff) {
  __shared__ float t[32][33];
  const int tx = threadIdx.x, ty = threadIdx.y;  // 32 x 8
  const int n0 = blockIdx.x * 32, k0 = blockIdx.y * 32;
#pragma unroll
  for (int i = 0; i < 4; i++) {
    int k = k0 + ty + i * 8;
    t[ty + i * 8][tx] = (k < K && n0 + tx < N) ? W[(size_t)k * N + n0 + tx] : 0.f;
  }
  __syncthreads();
#pragma unroll
  for (int i = 0; i < 4; i++) {
    int n = n0 + ty + i * 8;
    if (n < Npad && k0 + tx < K)
      Wt[(size_t)n * ldw + koff + k0 + tx] = __float2bfloat16(t[tx][ty + i * 8]);
  }
}

__global__ void conv_bf16_kernel(const float* __restrict__ src, __hip_bfloat16* __restrict__ dst,
                                 int n) {
  int i = blockIdx.x * 256 + threadIdx.x;
  if (i < n) dst[i] = __float2bfloat16(src[i]);
}

__global__ void bqaq_kernel(const float* __restrict__ b_q, const float* __restrict__ b_aq,
                            const __hip_bfloat16* __restrict__ Wt_aq, float* __restrict__ b_qaq) {
  int n = blockIdx.x * 256 + threadIdx.x;
  if (n >= DIN) return;
  const __hip_bfloat16* wr = Wt_aq + (size_t)n * DIN;
  float s = b_aq[n];
  for (int k = 0; k < DIN; k++) s += b_q[k] * __bfloat162float(wr[k]);
  b_qaq[n] = s;
}

// b_s1c[n] = b_s1[n] + sum_{k<1024} b_ao[k] * W_s1[k, n]   (n < 2048)
__global__ void bs1c_kernel(const float* __restrict__ b_s1, const float* __restrict__ b_ao,
                            const float* __restrict__ W_s1, float* __restrict__ b_s1c) {
  int n = blockIdx.x * 256 + threadIdx.x;
  if (n >= DMODEL) return;
  float s = b_s1[n];
  for (int k = 0; k < DIN; k++) s += b_ao[k] * W_s1[(size_t)k * DMODEL + n];
  b_s1c[n] = s;
}

// ---------------- big MFMA GEMM (precompute), XCD-chunked swizzle ----------
// TRANSC: 0 = row-major C[M,N]; 2 = attn layout;
//         3 = combined kh|vh attn layout (N=2048; col>=1024 -> vh region)
__device__ inline short8 load_chunk(const __hip_bfloat16* p) {
  return *reinterpret_cast<const short8*>(p);
}
__device__ inline short8 load_chunk(const float* p) {
  short8 r;
#pragma unroll
  for (int j = 0; j < 8; j++) r[j] = f2bs(p[j]);
  return r;
}

template <int TRANSC, typename TA, typename TC>
__global__ __launch_bounds__(256) void gemm_big(const TA* __restrict__ A,
                                                const __hip_bfloat16* __restrict__ Bt,
                                                const float* __restrict__ bias,
                                                TC* __restrict__ C, int M, int N, int K) {
  __shared__ short lsA[128 * 64];
  __shared__ short lsB[128 * 64];
  const int tid = threadIdx.x;
  const int l = tid & 63, w = tid >> 6;
  const int wr = (w >> 1) * 64, wc = (w & 1) * 64;
  const int nwg = gridDim.x * gridDim.y;
  const int flat = blockIdx.y * gridDim.x + blockIdx.x;
  const int wk = (flat & 7) * (nwg >> 3) + (flat >> 3);  // nwg % 8 == 0
  const int brow = (wk / gridDim.x) * 128, bcol = (wk % gridDim.x) * 128;
  f32x4 acc[4][4];
#pragma unroll
  for (int i = 0; i < 4; i++)
#pragma unroll
    for (int j = 0; j < 4; j++)
#pragma unroll
      for (int r = 0; r < 4; r++) acc[i][j][r] = 0.f;

  short8 ra[4], rb[4];
  auto gload = [&](int k0) {
#pragma unroll
    for (int q = 0; q < 4; q++) {
      int i = tid + q * 256;
      int row = i >> 3, c = i & 7;
      ra[q] = load_chunk(A + (size_t)(brow + row) * K + k0 + c * 8);
      rb[q] = load_chunk(Bt + (size_t)(bcol + row) * K + k0 + c * 8);
    }
  };
  auto lwrite = [&]() {
#pragma unroll
    for (int q = 0; q < 4; q++) {
      int i = tid + q * 256;
      int row = i >> 3, c = i & 7;
      int sw = c ^ (row & 7);
      *reinterpret_cast<short8*>(&lsA[row * 64 + sw * 8]) = ra[q];
      *reinterpret_cast<short8*>(&lsB[row * 64 + sw * 8]) = rb[q];
    }
  };
  gload(0);
  for (int k0 = 0; k0 < K; k0 += 64) {
    __syncthreads();
    lwrite();
    if (k0 + 64 < K) gload(k0 + 64);
    __syncthreads();
#pragma unroll
    for (int ks = 0; ks < 2; ks++) {
      short8 af[4], bfv[4];
#pragma unroll
      for (int mi = 0; mi < 4; mi++) {
        int row = wr + mi * 16 + (l & 15);
        int c = ks * 4 + (l >> 4);
        af[mi] = *reinterpret_cast<const short8*>(&lsA[row * 64 + (c ^ (row & 7)) * 8]);
      }
#pragma unroll
      for (int ni = 0; ni < 4; ni++) {
        int row = wc + ni * 16 + (l & 15);
        int c = ks * 4 + (l >> 4);
        bfv[ni] = *reinterpret_cast<const short8*>(&lsB[row * 64 + (c ^ (row & 7)) * 8]);
      }
#pragma unroll
      for (int mi = 0; mi < 4; mi++)
#pragma unroll
        for (int ni = 0; ni < 4; ni++)
          acc[mi][ni] =
              __builtin_amdgcn_mfma_f32_16x16x32_bf16(af[mi], bfv[ni], acc[mi][ni], 0, 0, 0);
    }
  }
#pragma unroll
  for (int mi = 0; mi < 4; mi++)
#pragma unroll
    for (int ni = 0; ni < 4; ni++)
#pragma unroll
      for (int r = 0; r < 4; r++) {
        int row = brow + wr + mi * 16 + (l >> 4) * 4 + r;
        int col = bcol + wc + ni * 16 + (l & 15);
        float v = acc[mi][ni][r];
        if (bias) v += bias[col];
        if (TRANSC == 2) {
          int bb = row >> 9, s = row & 511, hh = col >> 6, dd = col & 63;
          store_f(&C[(((size_t)(bb * 16 + hh) * 512) + s) * 64 + dd], v);
        } else if (TRANSC == 3) {
          int bb = row >> 9, s = row & 511, hh2 = col >> 6, dd = col & 63;
          size_t base = (hh2 >= 16) ? (size_t)B_ * S_ * DIN : 0;  // vh after kh
          store_f(&C[base + (((size_t)(bb * 16 + (hh2 & 15)) * 512) + s) * 64 + dd], v);
        } else {
          store_f(&C[(size_t)row * N + col], v);
        }
      }
}

// ---------------- LayerNorm (strided/typed output) ----------------
template <typename TOUT>
__global__ __launch_bounds__(256) void ln_kernel(const float* __restrict__ x,
                                                 const float* __restrict__ g,
                                                 const float* __restrict__ be,
                                                 TOUT* __restrict__ out, int C,
                                                 size_t row_stride, int col_stride) {
  const int row = blockIdx.x;
  const int tid = threadIdx.x;
  const float* xr = x + (size_t)row * C;
  float s = 0.f, s2 = 0.f;
  for (int c = tid; c < C; c += 256) {
    float v = xr[c];
    s += v;
    s2 += v * v;
  }
  __shared__ float r1[256], r2[256];
  r1[tid] = s;
  r2[tid] = s2;
  __syncthreads();
  for (int st = 128; st > 0; st >>= 1) {
    if (tid < st) {
      r1[tid] += r1[tid + st];
      r2[tid] += r2[tid + st];
    }
    __syncthreads();
  }
  float mean = r1[0] / C;
  float var = r2[0] / C - mean * mean;
  float inv = 1.0f / sqrtf(var + 1e-5f);
  for (int c = tid; c < C; c += 256) {
    float v = (xr[c] - mean) * inv * g[c] + be[c];
    store_f(&out[(size_t)row * row_stride + (size_t)c * col_stride], v);
  }
}

// ---------------- init kernels ----------------
__global__ void init_pre_kernel(const float* __restrict__ init_state,
                                __hip_bfloat16* __restrict__ pre) {
  int i = blockIdx.x * 256 + threadIdx.x;
  if (i >= B_ * DMODEL) return;
  int b = i >> 11, j = i & (DMODEL - 1);
  pre[(size_t)b * 3072 + DIN + j] = __float2bfloat16(init_state[j]);
}

__global__ void init_hist_kernel(const float* __restrict__ init_hist, float* __restrict__ hist) {
  int i = blockIdx.x * 256 + threadIdx.x;
  if (i >= B_ * DMODEL * DMEM) return;
  int m = i & (DMEM - 1);
  int bd = i >> 5;
  int d = bd & (DMODEL - 1);
  hist[(size_t)bd * HIST_W + m] = init_hist[d * DMEM + m];
}

__global__ void init_sync_kernel(const float* __restrict__ init_state,
                                 const float* __restrict__ decay_action,
                                 const float* __restrict__ decay_out,
                                 const int* __restrict__ la, const int* __restrict__ ra,
                                 const int* __restrict__ lo, const int* __restrict__ ro,
                                 float* __restrict__ aA, float* __restrict__ bA,
                                 float* __restrict__ aO, float* __restrict__ bO,
                                 __hip_bfloat16* __restrict__ syncA, float* __restrict__ rAv,
                                 float* __restrict__ rOv) {
  int i = blockIdx.x * 256 + threadIdx.x;
  if (i >= B_ * NSYNC) return;
  int j = i & (NSYNC - 1);
  if (i < NSYNC) {
    rAv[i] = expf(-fminf(fmaxf(decay_action[i], 0.f), 15.f));
    rOv[i] = expf(-fminf(fmaxf(decay_out[i], 0.f), 15.f));
  }
  float pA = init_state[la[j]] * init_state[ra[j]];
  aA[i] = pA;
  bA[i] = 1.f;
  syncA[i] = __float2bfloat16(pA);  // pA / sqrt(1)
  aO[i] = init_state[lo[j]] * init_state[ro[j]];
  bO[i] = 1.f;
}

// ---------------- 64xN-tile MFMA matmul body ----------------
template <typename EPI>
__device__ __forceinline__ void mm_tile64(const __hip_bfloat16* __restrict__ A, int lda,
                                          const __hip_bfloat16* __restrict__ Bt, int ldb,
                                          int bcol, int kb, int kchunk, int tid, short* lsA,
                                          short* lsB, EPI epi) {
  const int l = tid & 63, w = tid >> 6;
  f32x4 acc[4];
#pragma unroll
  for (int i = 0; i < 4; i++)
#pragma unroll
    for (int r = 0; r < 4; r++) acc[i][r] = 0.f;
  short8 ra[2], rb[2];
  auto gload = [&](int k0) {
#pragma unroll
    for (int q = 0; q < 2; q++) {
      int i = tid + q * 256;
      int row = i >> 3, c = i & 7;
      ra[q] = *reinterpret_cast<const short8*>(A + (size_t)row * lda + k0 + c * 8);
      rb[q] = *reinterpret_cast<const short8*>(Bt + (size_t)(bcol + row) * ldb + k0 + c * 8);
    }
  };
  auto lwrite = [&]() {
#pragma unroll
    for (int q = 0; q < 2; q++) {
      int i = tid + q * 256;
      int row = i >> 3, c = i & 7;
      int sw = c ^ (row & 7);
      *reinterpret_cast<short8*>(&lsA[row * 64 + sw * 8]) = ra[q];
      *reinterpret_cast<short8*>(&lsB[row * 64 + sw * 8]) = rb[q];
    }
  };
  gload(kb);
  for (int k0 = kb; k0 < kb + kchunk; k0 += 64) {
    __syncthreads();
    lwrite();
    if (k0 + 64 < kb + kchunk) gload(k0 + 64);
    __syncthreads();
#pragma unroll
    for (int ks = 0; ks < 2; ks++) {
      int rowa = w * 16 + (l & 15);
      int c = ks * 4 + (l >> 4);
      short8 af = *reinterpret_cast<const short8*>(&lsA[rowa * 64 + (c ^ (rowa & 7)) * 8]);
#pragma unroll
      for (int ni = 0; ni < 4; ni++) {
        int rowb = ni * 16 + (l & 15);
        short8 bfv = *reinterpret_cast<const short8*>(&lsB[rowb * 64 + (c ^ (rowb & 7)) * 8]);
        acc[ni] = __builtin_amdgcn_mfma_f32_16x16x32_bf16(af, bfv, acc[ni], 0, 0, 0);
      }
    }
  }
#pragma unroll
  for (int ni = 0; ni < 4; ni++)
#pragma unroll
    for (int r = 0; r < 4; r++) {
      int m = w * 16 + (l >> 4) * 4 + r;
      int n = bcol + ni * 16 + (l & 15);
      epi(m, n, acc[ni][r]);
    }
}

// ---------------- weight-product GEMM: C^T[n*ldc + m] = A[m,:] . Bt[n,:] ----
// grid (N/64, M/64); full K per block (K % 64 == 0). 64x64 tiles -> enough
// blocks to occupy the machine (fixes the 32-block starvation).
__global__ __launch_bounds__(256) void gemm_wt64(const __hip_bfloat16* __restrict__ A,
                                                 const __hip_bfloat16* __restrict__ Bt,
                                                 __hip_bfloat16* __restrict__ C, int ldc,
                                                 int K) {
  __shared__ short lsA[64 * 64];
  __shared__ short lsB[64 * 64];
  const int tid = threadIdx.x;
  const int nt = blockIdx.x, mt = blockIdx.y;
  const __hip_bfloat16* Ab = A + (size_t)mt * 64 * K;
  mm_tile64(Ab, K, Bt, K, nt * 64, 0, K, tid, lsA, lsB, [&](int m, int n, float v) {
    C[(size_t)n * ldc + mt * 64 + m] = __float2bfloat16(v);
  });
}

// ---------------- split-K partial GEMM (atomic-free) ----------------
__global__ __launch_bounds__(256) void gemm_part(const __hip_bfloat16* __restrict__ A, int lda,
                                                 const __hip_bfloat16* __restrict__ Bt, int ldb,
                                                 float* __restrict__ part, int N, int kchunk) {
  __shared__ short lsA[64 * 64];
  __shared__ short lsB[64 * 64];
  const int tid = threadIdx.x;
  const int nt = blockIdx.x, ks = blockIdx.y;
  mm_tile64(A, lda, Bt, ldb, nt * 64, ks * kchunk, kchunk, tid, lsA, lsB,
            [&](int m, int n, float v) { part[((size_t)(ks * 64 + m)) * N + n] = v; });
}

// reduce(KS) + bias + gelu -> h1 (bf16)
__global__ void s1_red_kernel(const float* __restrict__ part, const float* __restrict__ bias,
                              __hip_bfloat16* __restrict__ h1, int KS) {
  int i = blockIdx.x * 256 + threadIdx.x;  // 64*2048
  int m = i >> 11, n = i & 2047;
  float s = bias[n];
  for (int k = 0; k < KS; k++) s += part[((size_t)(k * 64 + m)) * DMODEL + n];
  h1[(size_t)m * DMODEL + n] = __float2bfloat16(gelu_f(s));
}

// reduce(KS) + bias + LayerNorm -> hist slot 32+t (one block per batch row)
__global__ __launch_bounds__(256) void s2_red_ln_kernel(const float* __restrict__ part,
                                                        const float* __restrict__ bias,
                                                        const float* __restrict__ g,
                                                        const float* __restrict__ be,
                                                        float* __restrict__ hist, int KS, int t) {
  __shared__ float r1[256], r2[256];
  const int b = blockIdx.x;
  const int tid = threadIdx.x;
  float v8[8];
  float s = 0.f, s2 = 0.f;
#pragma unroll
  for (int i = 0; i < 8; i++) {
    int n = tid + i * 256;
    float x = bias[n];
    for (int k = 0; k < KS; k++) x += part[((size_t)(k * 64 + b)) * DMODEL + n];
    v8[i] = x;
    s += x;
    s2 += x * x;
  }
  r1[tid] = s;
  r2[tid] = s2;
  __syncthreads();
  for (int st = 128; st > 0; st >>= 1) {
    if (tid < st) {
      r1[tid] += r1[tid + st];
      r2[tid] += r2[tid + st];
    }
    __syncthreads();
  }
  float mean = r1[0] / DMODEL;
  float var = r2[0] / DMODEL - mean * mean;
  float inv = 1.f / sqrtf(var + 1e-5f);
#pragma unroll
  for (int i = 0; i < 8; i++) {
    int n = tid + i * 256;
    float pa = (v8[i] - mean) * inv * g[n] + be[n];
    hist[((size_t)b * DMODEL + n) * HIST_W + 32 + t] = pa;
  }
}

// ---------------- attention (head-major K/V; fused qh split-K reduce) -------
// writes directly into pre[:, :1024]
__global__ __launch_bounds__(256) void attn_kernel(const float* __restrict__ qpart,
                                                   const float* __restrict__ b_qaq,
                                                   const __hip_bfloat16* __restrict__ kh,
                                                   const __hip_bfloat16* __restrict__ vh,
                                                   __hip_bfloat16* __restrict__ pre) {
  __shared__ float qs[64];
  __shared__ float wv[512];
  __shared__ float red[256];
  __shared__ float red2[2048];
  const int u = blockIdx.x;
  const int b = u >> 4, h = u & (NH - 1);
  const int tid = threadIdx.x;
  const __hip_bfloat16* Kp = kh + (size_t)u * (S_ * DH);
  const __hip_bfloat16* Vp = vh + (size_t)u * (S_ * DH);
  if (tid < DH) {
    int n = h * DH + tid;
    float s = b_qaq[n];
#pragma unroll
    for (int ks = 0; ks < 4; ks++) s += qpart[((size_t)(ks * 64 + b)) * DIN + n];
    qs[tid] = s;
  }
  __syncthreads();
  float sc[2];
#pragma unroll
  for (int r = 0; r < 2; ++r) {
    int s = tid + r * 256;
    const short8* kp = reinterpret_cast<const short8*>(Kp + (size_t)s * DH);
    float accv = 0.f;
#pragma unroll
    for (int q = 0; q < 8; ++q) {
      short8 kk = kp[q];
#pragma unroll
      for (int j = 0; j < 8; ++j) accv += qs[q * 8 + j] * bfs(kk[j]);
    }
    sc[r] = accv * 0.125f;
  }
  red[tid] = fmaxf(sc[0], sc[1]);
  __syncthreads();
  for (int st = 128; st > 0; st >>= 1) {
    if (tid < st) red[tid] = fmaxf(red[tid], red[tid + st]);
    __syncthreads();
  }
  const float mx = red[0];
  __syncthreads();
  float e0 = expf(sc[0] - mx), e1 = expf(sc[1] - mx);
  wv[tid] = e0;
  wv[tid + 256] = e1;
  red[tid] = e0 + e1;
  __syncthreads();
  for (int st = 128; st > 0; st >>= 1) {
    if (tid < st) red[tid] += red[tid + st];
    __syncthreads();
  }
  const float invZ = 1.f / red[0];
  __syncthreads();
  const int d8 = tid & 7, sg = tid >> 3;
  float pacc[8];
#pragma unroll
  for (int j = 0; j < 8; ++j) pacc[j] = 0.f;
  for (int s = sg; s < S_; s += 32) {
    float wgt = wv[s];
    short8 vvv = *reinterpret_cast<const short8*>(Vp + (size_t)s * DH + d8 * 8);
#pragma unroll
    for (int j = 0; j < 8; ++j) pacc[j] += wgt * bfs(vvv[j]);
  }
#pragma unroll
  for (int j = 0; j < 8; ++j) red2[sg * 64 + d8 * 8 + j] = pacc[j];
  __syncthreads();
  if (tid < DH) {
    float r = 0.f;
#pragma unroll
    for (int g2 = 0; g2 < 32; ++g2) r += red2[g2 * 64 + tid];
    pre[(size_t)b * 3072 + h * DH + tid] = __float2bfloat16(r * invZ);
  }
}

// ---------------- per-neuron NLM ----------------
__global__ __launch_bounds__(256) void nlm_kernel(const float* __restrict__ hist,
                                                  const float* __restrict__ W1,
                                                  const float* __restrict__ b1,
                                                  const float* __restrict__ W2,
                                                  const float* __restrict__ b2,
                                                  float* __restrict__ out, int t) {
  __shared__ float w1s[4096];
  __shared__ float b1s[128];
  const int tid = threadIdx.x;
  const int d0 = blockIdx.x * 4;
  for (int i = tid; i < 4096; i += 256) w1s[i] = W1[(size_t)d0 * 1024 + i];
  if (tid < 128) b1s[tid] = b1[d0 * 32 + tid];
  __syncthreads();
  const int b = tid & 63, dsub = tid >> 6;
  const int d = d0 + dsub;
  const float* hw = hist + ((size_t)(b * DMODEL + d)) * HIST_W + (t + 1);
  float win[DMEM];
#pragma unroll
  for (int m = 0; m < DMEM; ++m) win[m] = hw[m];
  const float* w1 = w1s + dsub * 1024;
  const float* bb = b1s + dsub * 32;
  const float* w2 = W2 + d * HNLM;
  float acc = 0.f;
  for (int h = 0; h < HNLM; ++h) {
    float s = bb[h];
#pragma unroll
    for (int m = 0; m < DMEM; ++m) s += win[m] * w1[m * HNLM + h];
    acc += fmaxf(s, 0.f) * w2[h];
  }
  out[(size_t)b * DMODEL + d] = acc + b2[d];
}

// ---------------- final fused kernel: LN -> sync updates -> pre pack ->
//   coalesced out-head GEMV + entropy. One block per batch b.
__global__ __launch_bounds__(256) void final_kernel(
    const float* __restrict__ nlmraw, const float* __restrict__ g_n,
    const float* __restrict__ be_n, const int* __restrict__ la, const int* __restrict__ ra,
    const int* __restrict__ lo, const int* __restrict__ ro, const float* __restrict__ rAv,
    const float* __restrict__ rOv, float* __restrict__ aA, float* __restrict__ bA,
    float* __restrict__ aO, float* __restrict__ bO, __hip_bfloat16* __restrict__ syncA,
    __hip_bfloat16* __restrict__ pre, const __hip_bfloat16* __restrict__ Wt_out,
    const float* __restrict__ b_out, float* __restrict__ outp, int t) {
  __shared__ float arow[2048];
  __shared__ float so_p[520];  // syncO with +1-per-64 pad (bank spread)
  __shared__ float pv[1024];
  __shared__ float red[256], red2[256];
  const int b = blockIdx.x;
  const int tid = threadIdx.x;
  const float* xr = nlmraw + (size_t)b * DMODEL;
  float xv[8];
  float s = 0.f, s2 = 0.f;
#pragma unroll
  for (int i = 0; i < 8; i++) {
    float x = xr[tid + i * 256];
    xv[i] = x;
    s += x;
    s2 += x * x;
  }
  red[tid] = s;
  red2[tid] = s2;
  __syncthreads();
  for (int st = 128; st > 0; st >>= 1) {
    if (tid < st) {
      red[tid] += red[tid + st];
      red2[tid] += red2[tid + st];
    }
    __syncthreads();
  }
  float mean = red[0] / DMODEL;
  float var = red2[0] / DMODEL - mean * mean;
  float inv = 1.f / sqrtf(var + 1e-5f);
  __syncthreads();
#pragma unroll
  for (int i = 0; i < 8; i++) {
    int n = tid + i * 256;
    float av = (xv[i] - mean) * inv * g_n[n] + be_n[n];
    arow[n] = av;
    pre[(size_t)b * 3072 + DIN + n] = __float2bfloat16(av);  // act for tick t+1
  }
  __syncthreads();
  for (int j = tid; j < NSYNC; j += 256) {
    size_t idx = (size_t)b * NSYNC + j;
    float pA = arow[la[j]] * arow[ra[j]];
    float r = rAv[j];
    float av2 = r * aA[idx] + pA, bv2 = r * bA[idx] + 1.f;
    aA[idx] = av2;
    bA[idx] = bv2;
    syncA[idx] = __float2bfloat16(av2 / sqrtf(bv2));  // syncA (t+1) -> global
    float pO = arow[lo[j]] * arow[ro[j]];
    float ro2 = rOv[j];
    float av3 = ro2 * aO[idx] + pO, bv3 = ro2 * bO[idx] + 1.f;
    aO[idx] = av3;
    bO[idx] = bv3;
    so_p[j + (j >> 6)] = av3 / sqrtf(bv3);  // syncO (t) in padded LDS
  }
  __syncthreads();
  // out head: 8 lanes per output row; per q, the 8 lanes read one contiguous
  // 128B short8 chunk of row n (fully-consumed lines); shfl-xor 3-step reduce.
  const int lk = tid & 7;   // k-slice within row
  const int rg = tid >> 3;  // row-group 0..31
  for (int it = 0; it < 32; ++it) {
    int n = it * 32 + rg;
    float sacc = 0.f;
    if (n < DOUT) {
      const short8* wr8 = reinterpret_cast<const short8*>(Wt_out + (size_t)n * NSYNC);
#pragma unroll
      for (int q = 0; q < 8; ++q) {
        short8 w8 = wr8[q * 8 + lk];
#pragma unroll
        for (int j = 0; j < 8; ++j) sacc += so_p[q * 65 + lk * 8 + j] * bfs(w8[j]);
      }
    }
    sacc += __shfl_xor(sacc, 1);
    sacc += __shfl_xor(sacc, 2);
    sacc += __shfl_xor(sacc, 4);
    if (lk == 0 && n < DOUT) pv[n] = sacc + b_out[n];
  }
  __syncthreads();
  float m = -1e30f;
  for (int o = tid; o < DOUT; o += 256) m = fmaxf(m, pv[o]);
  red[tid] = m;
  __syncthreads();
  for (int st = 128; st > 0; st >>= 1) {
    if (tid < st) red[tid] = fmaxf(red[tid], red[tid + st]);
    __syncthreads();
  }
  m = red[0];
  __syncthreads();
  float z = 0.f, s1 = 0.f;
  for (int o = tid; o < DOUT; o += 256) {
    float wv2 = pv[o] - m;
    float e = expf(wv2);
    z += e;
    s1 += e * wv2;
  }
  red[tid] = z;
  __syncthreads();
  for (int st = 128; st > 0; st >>= 1) {
    if (tid < st) red[tid] += red[tid + st];
    __syncthreads();
  }
  const float Z = red[0];
  __syncthreads();
  red[tid] = s1;
  __syncthreads();
  for (int st = 128; st > 0; st >>= 1) {
    if (tid < st) red[tid] += red[tid + st];
    __syncthreads();
  }
  const float S1 = red[0];
  const float ne = -(S1 / Z - logf(Z)) / 6.907755278982137f;
  for (int o = tid; o < DOUT; o += 256) outp[((size_t)b * DOUT + o) * TICKS + t] = pv[o];
  if (tid == 0) {
    float* c = outp + (size_t)B_ * DOUT * TICKS;
    c[b * 2 * TICKS + t] = ne;
    c[b * 2 * TICKS + TICKS + t] = 1.f - ne;
  }
}

// ---------------------------------------------------------------------------
extern "C" void kernel_launch(void* const* d_in, const int* in_sizes, int n_in,
                              void* d_out, int out_size, void* d_ws, size_t ws_size,
                              hipStream_t stream) {
  const float* x = (const float*)d_in[0];
  const float* W_kv = (const float*)d_in[1];
  const float* b_kv = (const float*)d_in[2];
  const float* g_kv = (const float*)d_in[3];
  const float* be_kv = (const float*)d_in[4];
  const float* W_q = (const float*)d_in[5];
  const float* b_q = (const float*)d_in[6];
  const float* W_aq = (const float*)d_in[7];
  const float* b_aq = (const float*)d_in[8];
  const float* W_ak = (const float*)d_in[9];
  const float* b_ak = (const float*)d_in[10];
  const float* W_av = (const float*)d_in[11];
  const float* b_av = (const float*)d_in[12];
  const float* W_ao = (const float*)d_in[13];
  const float* b_ao = (const float*)d_in[14];
  const float* W_s1 = (const float*)d_in[15];
  const float* b_s1 = (const float*)d_in[16];
  const float* W_s2 = (const float*)d_in[17];
  const float* b_s2 = (const float*)d_in[18];
  const float* g_s = (const float*)d_in[19];
  const float* be_s = (const float*)d_in[20];
  const float* W_n1 = (const float*)d_in[21];
  const float* b_n1 = (const float*)d_in[22];
  const float* W_n2 = (const float*)d_in[23];
  const float* b_n2 = (const float*)d_in[24];
  const float* g_n = (const float*)d_in[25];
  const float* be_n = (const float*)d_in[26];
  const float* init_state = (const float*)d_in[27];
  const float* init_hist = (const float*)d_in[28];
  const float* decay_action = (const float*)d_in[29];
  const float* decay_out = (const float*)d_in[30];
  const float* W_out = (const float*)d_in[31];
  const float* b_out = (const float*)d_in[32];
  const int* idx_la = (const int*)d_in[33];
  const int* idx_ra = (const int*)d_in[34];
  const int* idx_lo = (const int*)d_in[35];
  const int* idx_ro = (const int*)d_in[36];
  float* out = (float*)d_out;

  // ---- workspace carve ----
  char* wsb = (char*)d_ws;
  size_t off = 0;
  auto alloc = [&](size_t bytes) -> char* {
    char* p = wsb + off;
    off += (bytes + 255) & ~(size_t)255;
    return p;
  };
  const size_t MS = (size_t)B_ * S_;  // 32768
  char* regionA = alloc(MS * DIN * 4);  // kvraw fp32; later kh+vh bf16 (head-major)
  __hip_bfloat16* kv = (__hip_bfloat16*)alloc(MS * DIN * 2);
  float* histf = (float*)alloc((size_t)B_ * DMODEL * HIST_W * 4);
  __hip_bfloat16* Wt_kv = (__hip_bfloat16*)alloc((size_t)DIN * F_ * 2);
  __hip_bfloat16* Wt_akav = (__hip_bfloat16*)alloc((size_t)2 * DIN * DIN * 2);  // concat ak|av
  __hip_bfloat16* Wt_aq = (__hip_bfloat16*)alloc((size_t)DIN * DIN * 2);
  __hip_bfloat16* W_ao_b = (__hip_bfloat16*)alloc((size_t)DIN * DIN * 2);
  __hip_bfloat16* W_qb = (__hip_bfloat16*)alloc((size_t)NSYNC * DIN * 2);
  __hip_bfloat16* Wt_qaq = (__hip_bfloat16*)alloc((size_t)DIN * NSYNC * 2);
  __hip_bfloat16* Wts1top = (__hip_bfloat16*)alloc((size_t)DMODEL * DIN * 2);
  __hip_bfloat16* Wt_s1c = (__hip_bfloat16*)alloc((size_t)DMODEL * (DIN + DMODEL) * 2);
  __hip_bfloat16* Wt_s2 = (__hip_bfloat16*)alloc((size_t)DMODEL * DMODEL * 2);
  __hip_bfloat16* Wt_out = (__hip_bfloat16*)alloc((size_t)DOUT * NSYNC * 2);
  float* b_qaq = (float*)alloc(DIN * 4);
  float* b_s1c = (float*)alloc(DMODEL * 4);
  float* b_akav = (float*)alloc((size_t)2 * DIN * 4);
  float* partial = (float*)alloc((size_t)8 * 64 * DMODEL * 4);
  float* aA = (float*)alloc((size_t)B_ * NSYNC * 4);
  float* bA = (float*)alloc((size_t)B_ * NSYNC * 4);
  float* aO = (float*)alloc((size_t)B_ * NSYNC * 4);
  float* bO = (float*)alloc((size_t)B_ * NSYNC * 4);
  __hip_bfloat16* syncA = (__hip_bfloat16*)alloc((size_t)B_ * NSYNC * 2);
  __hip_bfloat16* pre = (__hip_bfloat16*)alloc((size_t)B_ * (DIN + DMODEL) * 2);
  __hip_bfloat16* h1 = (__hip_bfloat16*)alloc((size_t)B_ * DMODEL * 2);
  float* nlmraw = (float*)alloc((size_t)B_ * DMODEL * 4);
  float* rAv = (float*)alloc(NSYNC * 4);
  float* rOv = (float*)alloc(NSYNC * 4);

  float* kvraw = (float*)regionA;
  __hip_bfloat16* kh = (__hip_bfloat16*)regionA;                   // [b][h][s][d]
  __hip_bfloat16* vh = (__hip_bfloat16*)(regionA + MS * DIN * 2);  // [b][h][s][d]
  __hip_bfloat16* Wt_ak = Wt_akav;                                 // rows [0,1024)
  __hip_bfloat16* Wt_av = Wt_akav + (size_t)DIN * DIN;             // rows [1024,2048)

  dim3 t32x8(32, 8);
  // ---- weight prep ----
  transpose_bf16_kernel<<<dim3(F_ / 32, DIN / 32), t32x8, 0, stream>>>(W_kv, Wt_kv, F_, DIN, DIN,
                                                                       F_, 0);
  transpose_bf16_kernel<<<dim3(DIN / 32, DIN / 32), t32x8, 0, stream>>>(W_ak, Wt_ak, DIN, DIN,
                                                                        DIN, DIN, 0);
  transpose_bf16_kernel<<<dim3(DIN / 32, DIN / 32), t32x8, 0, stream>>>(W_av, Wt_av, DIN, DIN,
                                                                        DIN, DIN, 0);
  transpose_bf16_kernel<<<dim3(DIN / 32, DIN / 32), t32x8, 0, stream>>>(W_aq, Wt_aq, DIN, DIN,
                                                                        DIN, DIN, 0);
  // W_s1 top block transposed (for W_ao@W_s1top GEMM)
  transpose_bf16_kernel<<<dim3(DMODEL / 32, DIN / 32), t32x8, 0, stream>>>(W_s1, Wts1top, DIN,
                                                                           DMODEL, DMODEL, DIN, 0);
  // W_s1 bottom block -> Wt_s1c cols [1024, 3072)
  transpose_bf16_kernel<<<dim3(DMODEL / 32, DMODEL / 32), t32x8, 0, stream>>>(
      W_s1 + (size_t)DIN * DMODEL, Wt_s1c, DMODEL, DMODEL, DMODEL, DIN + DMODEL, DIN);
  transpose_bf16_kernel<<<dim3(DMODEL / 32, DMODEL / 32), t32x8, 0, stream>>>(W_s2, Wt_s2, DMODEL,
                                                                              DMODEL, DMODEL,
                                                                              DMODEL, 0);
  transpose_bf16_kernel<<<dim3((DOUT + 31) / 32, NSYNC / 32), t32x8, 0, stream>>>(
      W_out, Wt_out, NSYNC, DOUT, DOUT, NSYNC, 0);
  conv_bf16_kernel<<<(NSYNC * DIN + 255) / 256, 256, 0, stream>>>(W_q, W_qb, NSYNC * DIN);
  conv_bf16_kernel<<<(DIN * DIN + 255) / 256, 256, 0, stream>>>(W_ao, W_ao_b, DIN * DIN);
  bqaq_kernel<<<4, 256, 0, stream>>>(b_q, b_aq, Wt_aq, b_qaq);
  bs1c_kernel<<<8, 256, 0, stream>>>(b_s1, b_ao, W_s1, b_s1c);
  hipMemcpyAsync(b_akav, b_ak, DIN * 4, hipMemcpyDeviceToDevice, stream);
  hipMemcpyAsync(b_akav + DIN, b_av, DIN * 4, hipMemcpyDeviceToDevice, stream);

  // ---- precompute ----
  gemm_big<0, float, float><<<dim3(DIN / 128, MS / 128), 256, 0, stream>>>(x, Wt_kv, b_kv, kvraw,
                                                                           (int)MS, DIN, F_);
  ln_kernel<__hip_bfloat16><<<(int)MS, 256, 0, stream>>>(kvraw, g_kv, be_kv, kv, DIN, DIN, 1);
  // kh|vh combined: N=2048 vs concat(Wt_ak, Wt_av), TRANSC=3 routes halves
  gemm_big<3, __hip_bfloat16, __hip_bfloat16><<<dim3(2 * DIN / 128, MS / 128), 256, 0, stream>>>(
      kv, Wt_akav, b_akav, kh, (int)MS, 2 * DIN, DIN);
  // Wt_qaq = (W_q @ W_aq)^T : 64-tile, grid (1024/64, 512/64) = 128 blocks
  gemm_wt64<<<dim3(DIN / 64, NSYNC / 64), 256, 0, stream>>>(W_qb, Wt_aq, Wt_qaq, NSYNC, DIN);
  // Wt_s1c cols [0,1024): (W_ao @ W_s1top)^T, ldc=3072: 512 blocks
  gemm_wt64<<<dim3(DMODEL / 64, DIN / 64), 256, 0, stream>>>(W_ao_b, Wts1top, Wt_s1c,
                                                             DIN + DMODEL, DIN);

  // ---- state init ----
  init_pre_kernel<<<(B_ * DMODEL + 255) / 256, 256, 0, stream>>>(init_state, pre);
  init_hist_kernel<<<(B_ * DMODEL * DMEM + 255) / 256, 256, 0, stream>>>(init_hist, histf);
  init_sync_kernel<<<(B_ * NSYNC + 255) / 256, 256, 0, stream>>>(
      init_state, decay_action, decay_out, idx_la, idx_ra, idx_lo, idx_ro, aA, bA, aO, bO, syncA,
      rAv, rOv);

  // ---- tick loop: 8 kernels per tick, atomic-free ----
  for (int t = 0; t < TICKS; ++t) {
    // qh partials (K=512, KS=4, kchunk 128)
    gemm_part<<<dim3(16, 4), 256, 0, stream>>>(syncA, NSYNC, Wt_qaq, NSYNC, partial, DIN, 128);
    // attention (+fused qh reduce) -> pre[:, :1024]
    attn_kernel<<<B_ * NH, 256, 0, stream>>>(partial, b_qaq, kh, vh, pre);
    // s1 partials (K=3072, KS=8, kchunk 384) + reduce+gelu -> h1
    gemm_part<<<dim3(32, 8), 256, 0, stream>>>(pre, DIN + DMODEL, Wt_s1c, DIN + DMODEL, partial,
                                               DMODEL, 384);
    s1_red_kernel<<<512, 256, 0, stream>>>(partial, b_s1c, h1, 8);
    // s2 partials (K=2048, KS=8, kchunk 256) + reduce+LN -> hist slot 32+t
    gemm_part<<<dim3(32, 8), 256, 0, stream>>>(h1, DMODEL, Wt_s2, DMODEL, partial, DMODEL, 256);
    s2_red_ln_kernel<<<B_, 256, 0, stream>>>(partial, b_s2, g_s, be_s, histf, 8, t);
    nlm_kernel<<<DMODEL / 4, 256, 0, stream>>>(histf, W_n1, b_n1, W_n2, b_n2, nlmraw, t);
    final_kernel<<<B_, 256, 0, stream>>>(nlmraw, g_n, be_n, idx_la, idx_ra, idx_lo, idx_ro, rAv,
                                         rOv, aA, bA, aO, bO, syncA, pre, Wt_out, b_out, out, t);
  }
  (void)in_sizes; (void)n_in; (void)out_size; (void)ws_size;
}